// Round 1
// baseline (566.100 us; speedup 1.0000x reference)
//
#include <hip/hip_runtime.h>
#include <math.h>

// Problem constants (match reference)
static constexpr int B  = 16384;
static constexpr int F  = 256;
static constexpr int NQ = 2048;
static constexpr int DT = 256;
static constexpr int TS = 16;
static constexpr int KTOP = 8;
static constexpr int GH = 128;
static constexpr int SH = 128;
static constexpr int SPD = DT + TS;      // 272
static constexpr int SPH = 68;
static constexpr int CD  = DT + 3 + TS + 3; // 278
static constexpr int CH  = 69;

// ---------------------------------------------------------------------------
// Kernel 1: calibration + stem MLP -> x_cal[b,f]
// one thread per (b,f); block = one row (256 threads)
// ---------------------------------------------------------------------------
__global__ __launch_bounds__(256) void k_calib(
    const float* __restrict__ x_num, const float* __restrict__ center,
    const float* __restrict__ scale, const float* __restrict__ qs,
    const float* __restrict__ sw1, const float* __restrict__ sb1,
    const float* __restrict__ sw2, const float* __restrict__ sb2,
    const float* __restrict__ sw3, const float* __restrict__ sb3,
    float* __restrict__ x_cal)
{
    __shared__ float s_w1[48], s_b1[16], s_w2[256], s_b2[16], s_w3[16];
    const int tid = threadIdx.x;
    if (tid < 48) s_w1[tid] = sw1[tid];
    if (tid < 16) { s_b1[tid] = sb1[tid]; s_b2[tid] = sb2[tid]; s_w3[tid] = sw3[tid]; }
    s_w2[tid] = sw2[tid];
    __syncthreads();

    const int b = blockIdx.x;
    const int f = tid;
    const float x  = x_num[(long)b * F + f];
    const float xr = (x - center[f]) / scale[f];

    // searchsorted side='left' on column f: first idx with qs[idx,f] >= x
    int lo = 0, hi = NQ;
    while (lo < hi) {
        int mid = (lo + hi) >> 1;
        if (qs[(long)mid * F + f] < x) lo = mid + 1; else hi = mid;
    }
    float xq = (float)lo * (1.0f / (float)(NQ - 1));
    xq = fminf(xq, 1.0f);   // lo >= 0 always

    float h1[16];
#pragma unroll
    for (int j = 0; j < 16; ++j) {
        float v = s_b1[j] + x * s_w1[j] + xr * s_w1[16 + j] + xq * s_w1[32 + j];
        h1[j] = fmaxf(v, 0.0f);
    }
    float h2[16];
#pragma unroll
    for (int j = 0; j < 16; ++j) {
        float v = s_b2[j];
#pragma unroll
        for (int i = 0; i < 16; ++i) v += h1[i] * s_w2[i * 16 + j];
        h2[j] = fmaxf(v, 0.0f);
    }
    float o = sb3[0];
#pragma unroll
    for (int i = 0; i < 16; ++i) o += h2[i] * s_w3[i];
    const float resid = tanhf(o);
    x_cal[(long)b * F + f] = x + 0.1f * resid;
}

// ---------------------------------------------------------------------------
// Generic row-batched linear: out[b,n] = act(sum_k in[b,k] (*mul[b,k]) * W[k,n] + bias[n])
// blockDim = N, ROWS=8 rows per block, input rows staged in LDS
// ACT: 0 = relu, 1 = sigmoid
// ---------------------------------------------------------------------------
template <int K, int N, int ACT, bool MUL>
__global__ __launch_bounds__(N) void k_linear(
    const float* __restrict__ in, const float* __restrict__ mul,
    const float* __restrict__ W, const float* __restrict__ bias,
    float* __restrict__ out)
{
    constexpr int ROWS = 8;
    __shared__ __align__(16) float s_in[ROWS * K];
    const int tid = threadIdx.x;
    const long row0 = (long)blockIdx.x * ROWS;

    const float4* in4  = reinterpret_cast<const float4*>(in + row0 * K);
    const float4* mul4 = MUL ? reinterpret_cast<const float4*>(mul + row0 * K) : nullptr;
    float4* s4 = reinterpret_cast<float4*>(s_in);
    for (int idx = tid; idx < ROWS * K / 4; idx += N) {
        float4 v = in4[idx];
        if (MUL) {
            float4 m = mul4[idx];
            v.x *= m.x; v.y *= m.y; v.z *= m.z; v.w *= m.w;
        }
        s4[idx] = v;
    }
    __syncthreads();

    float acc[ROWS];
#pragma unroll
    for (int r = 0; r < ROWS; ++r) acc[r] = 0.0f;

    const float* Wc = W + tid;
    for (int k = 0; k < K; k += 4) {
        const float w0 = Wc[(k + 0) * N];
        const float w1 = Wc[(k + 1) * N];
        const float w2 = Wc[(k + 2) * N];
        const float w3 = Wc[(k + 3) * N];
#pragma unroll
        for (int r = 0; r < ROWS; ++r) {
            const float4 x4 = *reinterpret_cast<const float4*>(&s_in[r * K + k]);
            acc[r] += x4.x * w0 + x4.y * w1 + x4.z * w2 + x4.w * w3;
        }
    }
    const float bb = bias[tid];
#pragma unroll
    for (int r = 0; r < ROWS; ++r) {
        float v = acc[r] + bb;
        if (ACT == 0) v = fmaxf(v, 0.0f);
        else          v = 1.0f / (1.0f + expf(-v));
        out[(row0 + r) * N + tid] = v;
    }
}

// ---------------------------------------------------------------------------
// Kernel 4: per-row gate stats + stable top-8 + token MLP -> z_top[b,16], stats[b,4]
// one wave (64 threads) per row
// ---------------------------------------------------------------------------
__global__ __launch_bounds__(64) void k_topk(
    const float* __restrict__ g, const float* __restrict__ x_cal,
    const float* __restrict__ tw1, const float* __restrict__ tb1,
    const float* __restrict__ tw2, const float* __restrict__ tb2,
    float* __restrict__ z_top, float* __restrict__ stats)
{
    __shared__ float s_hm[16];
    const int b = blockIdx.x;
    const int lane = threadIdx.x;
    const long base = (long)b * F;

    float gv[4];
#pragma unroll
    for (int i = 0; i < 4; ++i) gv[i] = g[base + lane + 64 * i];

    // mean / max
    float s = gv[0] + gv[1] + gv[2] + gv[3];
    float mx = fmaxf(fmaxf(gv[0], gv[1]), fmaxf(gv[2], gv[3]));
    for (int m = 32; m; m >>= 1) {
        s  += __shfl_xor(s, m);
        mx  = fmaxf(mx, __shfl_xor(mx, m));
    }
    const float mean = s * (1.0f / 256.0f);
    // two-pass std (ddof=0)
    float vs = 0.0f;
#pragma unroll
    for (int i = 0; i < 4; ++i) { float d = gv[i] - mean; vs += d * d; }
    for (int m = 32; m; m >>= 1) vs += __shfl_xor(vs, m);
    const float stdv = sqrtf(vs * (1.0f / 256.0f));

    // stable top-8 (max value, ties -> lower index)
    float cur[4]; int curi[4];
#pragma unroll
    for (int i = 0; i < 4; ++i) { cur[i] = gv[i]; curi[i] = lane + 64 * i; }
    float tv[KTOP]; int ti[KTOP]; float vsum = 0.0f;
    for (int r = 0; r < KTOP; ++r) {
        float bv = cur[0]; int bi = curi[0];
#pragma unroll
        for (int i = 1; i < 4; ++i)
            if (cur[i] > bv || (cur[i] == bv && curi[i] < bi)) { bv = cur[i]; bi = curi[i]; }
        for (int m = 32; m; m >>= 1) {
            float ov = __shfl_xor(bv, m);
            int   oi = __shfl_xor(bi, m);
            if (ov > bv || (ov == bv && oi < bi)) { bv = ov; bi = oi; }
        }
        tv[r] = bv; ti[r] = bi; vsum += bv;
#pragma unroll
        for (int i = 0; i < 4; ++i) if (curi[i] == bi) cur[i] = -INFINITY;
    }
    const float denom = 1.0f / (vsum + 1e-6f);

    // token MLP: h[k][j] = relu(xw_k * tw1[j] + tb1[j]); z = (mean_k h)@tw2 + tb2
    if (lane < 16) {
        float hm = 0.0f;
        for (int k = 0; k < KTOP; ++k) {
            const float xk = x_cal[base + ti[k]];
            const float xw = xk * (tv[k] * denom);
            hm += fmaxf(xw * tw1[lane] + tb1[lane], 0.0f);
        }
        s_hm[lane] = hm * (1.0f / (float)KTOP);
    }
    __syncthreads();
    if (lane < 16) {
        float z = tb2[lane];
#pragma unroll
        for (int j = 0; j < 16; ++j) z += s_hm[j] * tw2[j * 16 + lane];
        z_top[(long)b * TS + lane] = z;
    }
    if (lane == 0) {
        stats[(long)b * 4 + 0] = mean;
        stats[(long)b * 4 + 1] = mx;
        stats[(long)b * 4 + 2] = stdv;
    }
}

// ---------------------------------------------------------------------------
// Kernel 6: tail — y_base, safe/spec/conf resMLPs, final combine. 8 rows/block.
// ---------------------------------------------------------------------------
__global__ __launch_bounds__(256) void k_tail(
    const float* __restrict__ h_base, const float* __restrict__ z_top,
    const float* __restrict__ stats,
    const float* __restrict__ base_w, const float* __restrict__ base_b,
    const float* __restrict__ safe_lg, const float* __restrict__ safe_lb,
    const float* __restrict__ safe_w1, const float* __restrict__ safe_b1,
    const float* __restrict__ safe_w2, const float* __restrict__ safe_b2,
    const float* __restrict__ spec_lg, const float* __restrict__ spec_lb,
    const float* __restrict__ spec_w1, const float* __restrict__ spec_b1,
    const float* __restrict__ spec_w2, const float* __restrict__ spec_b2,
    const float* __restrict__ conf_lg, const float* __restrict__ conf_lb,
    const float* __restrict__ conf_w1, const float* __restrict__ conf_b1,
    const float* __restrict__ conf_w2, const float* __restrict__ conf_b2,
    float* __restrict__ out)
{
    constexpr int ROWS = 8;
    __shared__ float s_hb[ROWS][256];
    __shared__ float s_ln[ROWS][256];
    __shared__ float s_sh[ROWS][128];
    __shared__ float s_sp[ROWS][288];
    __shared__ float s_sph[ROWS][SPH];
    __shared__ float s_cf[ROWS][288];
    __shared__ float s_cfh[ROWS][CH];
    __shared__ float s_scal[ROWS][8]; // 0 mu 1 rstd 2 ybase 3 dsafe 4 mu2 5 rstd2 6 dspec

    const int tid = threadIdx.x;
    const long row0 = (long)blockIdx.x * ROWS;

    // stage h_base
    for (int idx = tid; idx < ROWS * 256; idx += 256) {
        int r = idx >> 8, k = idx & 255;
        s_hb[r][k] = h_base[(row0 + r) * 256 + k];
    }
    __syncthreads();

    // per-row: mean, y_base (32-lane groups, r = tid>>5)
    {
        const int r = tid >> 5, l = tid & 31;
        float sum = 0.0f, ysum = 0.0f;
#pragma unroll
        for (int i = 0; i < 8; ++i) {
            int k = l + 32 * i;
            float v = s_hb[r][k];
            sum += v; ysum += v * base_w[k];
        }
        for (int m = 16; m; m >>= 1) { sum += __shfl_xor(sum, m); ysum += __shfl_xor(ysum, m); }
        const float mu = sum * (1.0f / 256.0f);
        float var = 0.0f;
#pragma unroll
        for (int i = 0; i < 8; ++i) {
            int k = l + 32 * i;
            float d = s_hb[r][k] - mu; var += d * d;
        }
        for (int m = 16; m; m >>= 1) var += __shfl_xor(var, m);
        if (l == 0) {
            s_scal[r][0] = mu;
            s_scal[r][1] = rsqrtf(var * (1.0f / 256.0f) + 1e-5f);
            s_scal[r][2] = ysum + base_b[0];
        }
    }
    __syncthreads();

    // ln for safe head
    for (int idx = tid; idx < ROWS * 256; idx += 256) {
        int r = idx >> 8, k = idx & 255;
        s_ln[r][k] = (s_hb[r][k] - s_scal[r][0]) * s_scal[r][1] * safe_lg[k] + safe_lb[k];
    }
    __syncthreads();

    // safe hidden: N=128, each thread 4 rows
    {
        const int n = tid & 127, half = tid >> 7;
        float acc[4] = {0, 0, 0, 0};
        for (int k = 0; k < 256; ++k) {
            const float w = safe_w1[k * 128 + n];
#pragma unroll
            for (int rr = 0; rr < 4; ++rr) acc[rr] += s_ln[half * 4 + rr][k] * w;
        }
        const float bb = safe_b1[n];
#pragma unroll
        for (int rr = 0; rr < 4; ++rr)
            s_sh[half * 4 + rr][n] = fmaxf(acc[rr] + bb, 0.0f);
    }
    __syncthreads();

    // d_safe per row
    {
        const int r = tid >> 5, l = tid & 31;
        float ds = 0.0f;
#pragma unroll
        for (int i = 0; i < 4; ++i) {
            int j = l + 32 * i;
            ds += s_sh[r][j] * safe_w2[j];
        }
        for (int m = 16; m; m >>= 1) ds += __shfl_xor(ds, m);
        if (l == 0) s_scal[r][3] = ds + safe_b2[0];
    }
    __syncthreads();

    // spec_in = [h_base, z_top] (272)
    for (int idx = tid; idx < ROWS * SPD; idx += 256) {
        int r = idx / SPD, k = idx - r * SPD;
        s_sp[r][k] = (k < 256) ? s_hb[r][k] : z_top[(row0 + r) * TS + (k - 256)];
    }
    __syncthreads();
    {   // LN stats over 272
        const int r = tid >> 5, l = tid & 31;
        float sum = 0.0f;
#pragma unroll
        for (int i = 0; i < 9; ++i) { int k = l + 32 * i; if (k < SPD) sum += s_sp[r][k]; }
        for (int m = 16; m; m >>= 1) sum += __shfl_xor(sum, m);
        const float mu = sum * (1.0f / (float)SPD);
        float var = 0.0f;
#pragma unroll
        for (int i = 0; i < 9; ++i) { int k = l + 32 * i; if (k < SPD) { float d = s_sp[r][k] - mu; var += d * d; } }
        for (int m = 16; m; m >>= 1) var += __shfl_xor(var, m);
        if (l == 0) { s_scal[r][4] = mu; s_scal[r][5] = rsqrtf(var * (1.0f / (float)SPD) + 1e-5f); }
    }
    __syncthreads();
    for (int idx = tid; idx < ROWS * SPD; idx += 256) {
        int r = idx / SPD, k = idx - r * SPD;
        s_sp[r][k] = (s_sp[r][k] - s_scal[r][4]) * s_scal[r][5] * spec_lg[k] + spec_lb[k];
    }
    __syncthreads();
    // spec hidden: 68 cols, thread<68 handles all rows
    if (tid < SPH) {
        float acc[ROWS];
#pragma unroll
        for (int r = 0; r < ROWS; ++r) acc[r] = 0.0f;
        for (int k = 0; k < SPD; ++k) {
            const float w = spec_w1[k * SPH + tid];
#pragma unroll
            for (int r = 0; r < ROWS; ++r) acc[r] += s_sp[r][k] * w;
        }
        const float bb = spec_b1[tid];
#pragma unroll
        for (int r = 0; r < ROWS; ++r) s_sph[r][tid] = fmaxf(acc[r] + bb, 0.0f);
    }
    __syncthreads();
    {   // d_spec per row
        const int r = tid >> 5, l = tid & 31;
        float ds = 0.0f;
#pragma unroll
        for (int i = 0; i < 3; ++i) { int j = l + 32 * i; if (j < SPH) ds += s_sph[r][j] * spec_w2[j]; }
        for (int m = 16; m; m >>= 1) ds += __shfl_xor(ds, m);
        if (l == 0) s_scal[r][6] = ds + spec_b2[0];
    }
    __syncthreads();

    // conf_in (278): h_base | y_base | mean | max | std | z_top | |dsafe| | |dspec|
    for (int idx = tid; idx < ROWS * CD; idx += 256) {
        int r = idx / CD, k = idx - r * CD;
        float v;
        if (k < 256)       v = s_hb[r][k];
        else if (k == 256) v = s_scal[r][2];
        else if (k == 257) v = stats[(row0 + r) * 4 + 0];
        else if (k == 258) v = stats[(row0 + r) * 4 + 1];
        else if (k == 259) v = stats[(row0 + r) * 4 + 2];
        else if (k < 276)  v = z_top[(row0 + r) * TS + (k - 260)];
        else if (k == 276) v = fabsf(s_scal[r][3]);
        else               v = fabsf(s_scal[r][6]);
        s_cf[r][k] = v;
    }
    __syncthreads();
    {   // LN stats over 278
        const int r = tid >> 5, l = tid & 31;
        float sum = 0.0f;
#pragma unroll
        for (int i = 0; i < 9; ++i) { int k = l + 32 * i; if (k < CD) sum += s_cf[r][k]; }
        for (int m = 16; m; m >>= 1) sum += __shfl_xor(sum, m);
        const float mu = sum * (1.0f / (float)CD);
        float var = 0.0f;
#pragma unroll
        for (int i = 0; i < 9; ++i) { int k = l + 32 * i; if (k < CD) { float d = s_cf[r][k] - mu; var += d * d; } }
        for (int m = 16; m; m >>= 1) var += __shfl_xor(var, m);
        if (l == 0) { s_scal[r][4] = mu; s_scal[r][5] = rsqrtf(var * (1.0f / (float)CD) + 1e-5f); }
    }
    __syncthreads();
    for (int idx = tid; idx < ROWS * CD; idx += 256) {
        int r = idx / CD, k = idx - r * CD;
        s_cf[r][k] = (s_cf[r][k] - s_scal[r][4]) * s_scal[r][5] * conf_lg[k] + conf_lb[k];
    }
    __syncthreads();
    // conf hidden: 69 cols
    if (tid < CH) {
        float acc[ROWS];
#pragma unroll
        for (int r = 0; r < ROWS; ++r) acc[r] = 0.0f;
        for (int k = 0; k < CD; ++k) {
            const float w = conf_w1[k * CH + tid];
#pragma unroll
            for (int r = 0; r < ROWS; ++r) acc[r] += s_cf[r][k] * w;
        }
        const float bb = conf_b1[tid];
#pragma unroll
        for (int r = 0; r < ROWS; ++r) s_cfh[r][tid] = fmaxf(acc[r] + bb, 0.0f);
    }
    __syncthreads();
    {   // gamma + final
        const int r = tid >> 5, l = tid & 31;
        float cs = 0.0f;
#pragma unroll
        for (int i = 0; i < 3; ++i) { int j = l + 32 * i; if (j < CH) cs += s_cfh[r][j] * conf_w2[j]; }
        for (int m = 16; m; m >>= 1) cs += __shfl_xor(cs, m);
        if (l == 0) {
            const float gamma = 1.0f / (1.0f + expf(-(cs + conf_b2[0])));
            out[row0 + r] = s_scal[r][2] + s_scal[r][3] + gamma * s_scal[r][6];
        }
    }
}

// ---------------------------------------------------------------------------
extern "C" void kernel_launch(void* const* d_in, const int* in_sizes, int n_in,
                              void* d_out, int out_size, void* d_ws, size_t ws_size,
                              hipStream_t stream)
{
    const float* x_num   = (const float*)d_in[0];
    const float* center  = (const float*)d_in[1];
    const float* scale   = (const float*)d_in[2];
    const float* qs      = (const float*)d_in[3];
    const float* stem_w1 = (const float*)d_in[4];
    const float* stem_b1 = (const float*)d_in[5];
    const float* stem_w2 = (const float*)d_in[6];
    const float* stem_b2 = (const float*)d_in[7];
    const float* stem_w3 = (const float*)d_in[8];
    const float* stem_b3 = (const float*)d_in[9];
    const float* gate_w1 = (const float*)d_in[10];
    const float* gate_b1 = (const float*)d_in[11];
    const float* gate_w2 = (const float*)d_in[12];
    const float* gate_b2 = (const float*)d_in[13];
    const float* bb_w    = (const float*)d_in[14];
    const float* bb_b    = (const float*)d_in[15];
    const float* base_w  = (const float*)d_in[16];
    const float* base_b  = (const float*)d_in[17];
    const float* safe_lg = (const float*)d_in[18];
    const float* safe_lb = (const float*)d_in[19];
    const float* safe_w1 = (const float*)d_in[20];
    const float* safe_b1 = (const float*)d_in[21];
    const float* safe_w2 = (const float*)d_in[22];
    const float* safe_b2 = (const float*)d_in[23];
    const float* top_w1  = (const float*)d_in[24];
    const float* top_b1  = (const float*)d_in[25];
    const float* top_w2  = (const float*)d_in[26];
    const float* top_b2  = (const float*)d_in[27];
    const float* spec_lg = (const float*)d_in[28];
    const float* spec_lb = (const float*)d_in[29];
    const float* spec_w1 = (const float*)d_in[30];
    const float* spec_b1 = (const float*)d_in[31];
    const float* spec_w2 = (const float*)d_in[32];
    const float* spec_b2 = (const float*)d_in[33];
    const float* conf_lg = (const float*)d_in[34];
    const float* conf_lb = (const float*)d_in[35];
    const float* conf_w1 = (const float*)d_in[36];
    const float* conf_b1 = (const float*)d_in[37];
    const float* conf_w2 = (const float*)d_in[38];
    const float* conf_b2 = (const float*)d_in[39];

    float* ws    = (float*)d_ws;
    float* x_cal = ws;                       // B*256
    float* g_h   = x_cal + (long)B * 256;    // B*128
    float* g     = g_h   + (long)B * 128;    // B*256
    float* h_b   = g     + (long)B * 256;    // B*256
    float* z_top = h_b   + (long)B * 256;    // B*16
    float* stats = z_top + (long)B * 16;     // B*4
    float* out   = (float*)d_out;

    k_calib<<<B, 256, 0, stream>>>(x_num, center, scale, qs,
                                   stem_w1, stem_b1, stem_w2, stem_b2, stem_w3, stem_b3,
                                   x_cal);
    k_linear<256, 128, 0, false><<<B / 8, 128, 0, stream>>>(x_cal, nullptr, gate_w1, gate_b1, g_h);
    k_linear<128, 256, 1, false><<<B / 8, 256, 0, stream>>>(g_h, nullptr, gate_w2, gate_b2, g);
    k_topk<<<B, 64, 0, stream>>>(g, x_cal, top_w1, top_b1, top_w2, top_b2, z_top, stats);
    k_linear<256, 256, 0, true><<<B / 8, 256, 0, stream>>>(x_cal, g, bb_w, bb_b, h_b);
    k_tail<<<B / 8, 256, 0, stream>>>(h_b, z_top, stats,
                                      base_w, base_b,
                                      safe_lg, safe_lb, safe_w1, safe_b1, safe_w2, safe_b2,
                                      spec_lg, spec_lb, spec_w1, spec_b1, spec_w2, spec_b2,
                                      conf_lg, conf_lb, conf_w1, conf_b1, conf_w2, conf_b2,
                                      out);
}

// Round 2
// 525.621 us; speedup vs baseline: 1.0770x; 1.0770x over previous
//
#include <hip/hip_runtime.h>
#include <math.h>

static constexpr int B  = 16384;
static constexpr int F  = 256;
static constexpr int NQ = 2048;
static constexpr int TS = 16;
static constexpr int KTOP = 8;
static constexpr int SPD = 272;   // 256 + 16
static constexpr int SPH = 68;
static constexpr int CD  = 278;   // 256+1+3+16+2
static constexpr int CH  = 69;

// ---------------------------------------------------------------------------
// Kernel 1: calibration + stem MLP -> x_cal[b,f]   (unchanged from R0)
// ---------------------------------------------------------------------------
__global__ __launch_bounds__(256) void k_calib(
    const float* __restrict__ x_num, const float* __restrict__ center,
    const float* __restrict__ scale, const float* __restrict__ qs,
    const float* __restrict__ sw1, const float* __restrict__ sb1,
    const float* __restrict__ sw2, const float* __restrict__ sb2,
    const float* __restrict__ sw3, const float* __restrict__ sb3,
    float* __restrict__ x_cal)
{
    __shared__ float s_w1[48], s_b1[16], s_w2[256], s_b2[16], s_w3[16];
    const int tid = threadIdx.x;
    if (tid < 48) s_w1[tid] = sw1[tid];
    if (tid < 16) { s_b1[tid] = sb1[tid]; s_b2[tid] = sb2[tid]; s_w3[tid] = sw3[tid]; }
    s_w2[tid] = sw2[tid];
    __syncthreads();

    const int b = blockIdx.x;
    const int f = tid;
    const float x  = x_num[(long)b * F + f];
    const float xr = (x - center[f]) / scale[f];

    int lo = 0, hi = NQ;
    while (lo < hi) {
        int mid = (lo + hi) >> 1;
        if (qs[(long)mid * F + f] < x) lo = mid + 1; else hi = mid;
    }
    float xq = fminf((float)lo * (1.0f / (float)(NQ - 1)), 1.0f);

    float h1[16];
#pragma unroll
    for (int j = 0; j < 16; ++j)
        h1[j] = fmaxf(s_b1[j] + x * s_w1[j] + xr * s_w1[16 + j] + xq * s_w1[32 + j], 0.0f);
    float h2[16];
#pragma unroll
    for (int j = 0; j < 16; ++j) {
        float v = s_b2[j];
#pragma unroll
        for (int i = 0; i < 16; ++i) v += h1[i] * s_w2[i * 16 + j];
        h2[j] = fmaxf(v, 0.0f);
    }
    float o = sb3[0];
#pragma unroll
    for (int i = 0; i < 16; ++i) o += h2[i] * s_w3[i];
    x_cal[(long)b * F + f] = x + 0.1f * tanhf(o);
}

// ---------------------------------------------------------------------------
// Row-batched linear, ROWS=16, one weight column per thread.
// Activation row values are read as wave-uniform broadcast ds_read_b128.
// ACT: 0 relu, 1 sigmoid.  blockDim == N.
// ---------------------------------------------------------------------------
template <int K, int N, int ACT, bool MUL>
__global__ __launch_bounds__(N) void k_linear2(
    const float* __restrict__ in, const float* __restrict__ mul,
    const float* __restrict__ W, const float* __restrict__ bias,
    float* __restrict__ out)
{
    constexpr int ROWS = 16;
    __shared__ __align__(16) float s_in[ROWS * K];
    const int tid = threadIdx.x;
    const long row0 = (long)blockIdx.x * ROWS;

    const float4* in4  = reinterpret_cast<const float4*>(in + row0 * K);
    const float4* mul4 = MUL ? reinterpret_cast<const float4*>(mul + row0 * K) : nullptr;
    float4* s4 = reinterpret_cast<float4*>(s_in);
    for (int idx = tid; idx < ROWS * K / 4; idx += N) {
        float4 v = in4[idx];
        if (MUL) {
            float4 m = mul4[idx];
            v.x *= m.x; v.y *= m.y; v.z *= m.z; v.w *= m.w;
        }
        s4[idx] = v;
    }
    __syncthreads();

    float acc[ROWS];
#pragma unroll
    for (int r = 0; r < ROWS; ++r) acc[r] = 0.0f;

    const float* Wc = W + tid;
    for (int k = 0; k < K; k += 4) {
        const float w0 = Wc[(k + 0) * N];
        const float w1 = Wc[(k + 1) * N];
        const float w2 = Wc[(k + 2) * N];
        const float w3 = Wc[(k + 3) * N];
#pragma unroll
        for (int r = 0; r < ROWS; ++r) {
            const float4 x4 = *reinterpret_cast<const float4*>(&s_in[r * K + k]);
            acc[r] += x4.x * w0 + x4.y * w1 + x4.z * w2 + x4.w * w3;
        }
    }
    const float bb = bias[tid];
#pragma unroll
    for (int r = 0; r < ROWS; ++r) {
        float v = acc[r] + bb;
        if (ACT == 0) v = fmaxf(v, 0.0f);
        else          v = 1.0f / (1.0f + expf(-v));
        out[(row0 + r) * N + tid] = v;
    }
}

// ---------------------------------------------------------------------------
// Kernel: per-row gate stats + stable top-8 + token MLP (unchanged from R0)
// ---------------------------------------------------------------------------
__global__ __launch_bounds__(64) void k_topk(
    const float* __restrict__ g, const float* __restrict__ x_cal,
    const float* __restrict__ tw1, const float* __restrict__ tb1,
    const float* __restrict__ tw2, const float* __restrict__ tb2,
    float* __restrict__ z_top, float* __restrict__ stats)
{
    __shared__ float s_hm[16];
    const int b = blockIdx.x;
    const int lane = threadIdx.x;
    const long base = (long)b * F;

    float gv[4];
#pragma unroll
    for (int i = 0; i < 4; ++i) gv[i] = g[base + lane + 64 * i];

    float s = gv[0] + gv[1] + gv[2] + gv[3];
    float mx = fmaxf(fmaxf(gv[0], gv[1]), fmaxf(gv[2], gv[3]));
    for (int m = 32; m; m >>= 1) {
        s  += __shfl_xor(s, m);
        mx  = fmaxf(mx, __shfl_xor(mx, m));
    }
    const float mean = s * (1.0f / 256.0f);
    float vs = 0.0f;
#pragma unroll
    for (int i = 0; i < 4; ++i) { float d = gv[i] - mean; vs += d * d; }
    for (int m = 32; m; m >>= 1) vs += __shfl_xor(vs, m);
    const float stdv = sqrtf(vs * (1.0f / 256.0f));

    float cur[4]; int curi[4];
#pragma unroll
    for (int i = 0; i < 4; ++i) { cur[i] = gv[i]; curi[i] = lane + 64 * i; }
    float tv[KTOP]; int ti[KTOP]; float vsum = 0.0f;
    for (int r = 0; r < KTOP; ++r) {
        float bv = cur[0]; int bi = curi[0];
#pragma unroll
        for (int i = 1; i < 4; ++i)
            if (cur[i] > bv || (cur[i] == bv && curi[i] < bi)) { bv = cur[i]; bi = curi[i]; }
        for (int m = 32; m; m >>= 1) {
            float ov = __shfl_xor(bv, m);
            int   oi = __shfl_xor(bi, m);
            if (ov > bv || (ov == bv && oi < bi)) { bv = ov; bi = oi; }
        }
        tv[r] = bv; ti[r] = bi; vsum += bv;
#pragma unroll
        for (int i = 0; i < 4; ++i) if (curi[i] == bi) cur[i] = -INFINITY;
    }
    const float denom = 1.0f / (vsum + 1e-6f);

    if (lane < 16) {
        float hm = 0.0f;
        for (int k = 0; k < KTOP; ++k) {
            const float xk = x_cal[base + ti[k]];
            const float xw = xk * (tv[k] * denom);
            hm += fmaxf(xw * tw1[lane] + tb1[lane], 0.0f);
        }
        s_hm[lane] = hm * (1.0f / (float)KTOP);
    }
    __syncthreads();
    if (lane < 16) {
        float z = tb2[lane];
#pragma unroll
        for (int j = 0; j < 16; ++j) z += s_hm[j] * tw2[j * 16 + lane];
        z_top[(long)b * TS + lane] = z;
    }
    if (lane == 0) {
        stats[(long)b * 4 + 0] = mean;
        stats[(long)b * 4 + 1] = mx;
        stats[(long)b * 4 + 2] = stdv;
    }
}

__device__ inline float wave_red_sum(float v) {
    for (int m = 32; m; m >>= 1) v += __shfl_xor(v, m);
    return v;
}

// ---------------------------------------------------------------------------
// k_safe: y_base + LN(h_base) + 256->128 relu + dot -> dsafe, yb
// blockDim 128, ROWS=16
// ---------------------------------------------------------------------------
__global__ __launch_bounds__(128) void k_safe(
    const float* __restrict__ h_base,
    const float* __restrict__ base_w, const float* __restrict__ base_b,
    const float* __restrict__ lg, const float* __restrict__ lb,
    const float* __restrict__ w1, const float* __restrict__ b1,
    const float* __restrict__ w2, const float* __restrict__ b2,
    float* __restrict__ yb, float* __restrict__ dsafe)
{
    constexpr int ROWS = 16;
    __shared__ __align__(16) float s_h[ROWS * 256];
    __shared__ float s_scal[ROWS][2];
    __shared__ float s_red[ROWS][2];
    const int tid = threadIdx.x;
    const long row0 = (long)blockIdx.x * ROWS;

    const float4* in4 = reinterpret_cast<const float4*>(h_base + row0 * 256);
    float4* s4 = reinterpret_cast<float4*>(s_h);
    for (int idx = tid; idx < ROWS * 64; idx += 128) s4[idx] = in4[idx];
    __syncthreads();

    // row stats with 8-lane groups: row = tid>>3, lane8 = tid&7
    {
        const int r = tid >> 3, l8 = tid & 7;
        float sum = 0.0f, ysum = 0.0f;
#pragma unroll
        for (int i = 0; i < 32; ++i) {
            int k = l8 + 8 * i;
            float v = s_h[r * 256 + k];
            sum += v; ysum += v * base_w[k];
        }
        for (int m = 4; m; m >>= 1) { sum += __shfl_xor(sum, m); ysum += __shfl_xor(ysum, m); }
        const float mu = sum * (1.0f / 256.0f);
        float var = 0.0f;
#pragma unroll
        for (int i = 0; i < 32; ++i) {
            int k = l8 + 8 * i;
            float d = s_h[r * 256 + k] - mu; var += d * d;
        }
        for (int m = 4; m; m >>= 1) var += __shfl_xor(var, m);
        if (l8 == 0) {
            s_scal[r][0] = mu;
            s_scal[r][1] = rsqrtf(var * (1.0f / 256.0f) + 1e-5f);
            yb[row0 + r] = ysum + base_b[0];
        }
    }
    __syncthreads();
    for (int idx = tid; idx < ROWS * 256; idx += 128) {
        int r = idx >> 8, k = idx & 255;
        s_h[idx] = (s_h[idx] - s_scal[r][0]) * s_scal[r][1] * lg[k] + lb[k];
    }
    __syncthreads();

    // GEMM 256 -> 128, col = tid
    float acc[ROWS];
#pragma unroll
    for (int r = 0; r < ROWS; ++r) acc[r] = 0.0f;
    const float* Wc = w1 + tid;
    for (int k = 0; k < 256; k += 4) {
        const float w0 = Wc[(k + 0) * 128];
        const float wv1 = Wc[(k + 1) * 128];
        const float wv2 = Wc[(k + 2) * 128];
        const float wv3 = Wc[(k + 3) * 128];
#pragma unroll
        for (int r = 0; r < ROWS; ++r) {
            const float4 x4 = *reinterpret_cast<const float4*>(&s_h[r * 256 + k]);
            acc[r] += x4.x * w0 + x4.y * wv1 + x4.z * wv2 + x4.w * wv3;
        }
    }
    const float bb = b1[tid], wo = w2[tid];
    const int wave = tid >> 6;
#pragma unroll
    for (int r = 0; r < ROWS; ++r) {
        float p = fmaxf(acc[r] + bb, 0.0f) * wo;
        p = wave_red_sum(p);
        if ((tid & 63) == 0) s_red[r][wave] = p;
    }
    __syncthreads();
    if (tid < ROWS) dsafe[row0 + tid] = s_red[tid][0] + s_red[tid][1] + b2[0];
}

// ---------------------------------------------------------------------------
// k_spec: LN([h_base|z_top]) + 272->68 relu + dot -> dspec
// blockDim 128, ROWS=16
// ---------------------------------------------------------------------------
__global__ __launch_bounds__(128) void k_spec(
    const float* __restrict__ h_base, const float* __restrict__ z_top,
    const float* __restrict__ lg, const float* __restrict__ lb,
    const float* __restrict__ w1, const float* __restrict__ b1,
    const float* __restrict__ w2, const float* __restrict__ b2,
    float* __restrict__ dspec)
{
    constexpr int ROWS = 16;
    __shared__ __align__(16) float s_x[ROWS * SPD];
    __shared__ float s_scal[ROWS][2];
    __shared__ float s_red[ROWS][2];
    const int tid = threadIdx.x;
    const long row0 = (long)blockIdx.x * ROWS;

    for (int idx = tid; idx < ROWS * 64; idx += 128) {
        int r = idx >> 6, q = idx & 63;
        *reinterpret_cast<float4*>(&s_x[r * SPD + q * 4]) =
            *reinterpret_cast<const float4*>(&h_base[(row0 + r) * 256 + q * 4]);
    }
    for (int idx = tid; idx < ROWS * TS; idx += 128) {
        int r = idx >> 4, j = idx & 15;
        s_x[r * SPD + 256 + j] = z_top[(row0 + r) * TS + j];
    }
    __syncthreads();
    {
        const int r = tid >> 3, l8 = tid & 7;
        float sum = 0.0f;
#pragma unroll
        for (int i = 0; i < 34; ++i) sum += s_x[r * SPD + l8 + 8 * i];
        for (int m = 4; m; m >>= 1) sum += __shfl_xor(sum, m);
        const float mu = sum * (1.0f / (float)SPD);
        float var = 0.0f;
#pragma unroll
        for (int i = 0; i < 34; ++i) { float d = s_x[r * SPD + l8 + 8 * i] - mu; var += d * d; }
        for (int m = 4; m; m >>= 1) var += __shfl_xor(var, m);
        if (l8 == 0) { s_scal[r][0] = mu; s_scal[r][1] = rsqrtf(var * (1.0f / (float)SPD) + 1e-5f); }
    }
    __syncthreads();
    for (int idx = tid; idx < ROWS * SPD; idx += 128) {
        int r = idx / SPD, k = idx - r * SPD;
        s_x[idx] = (s_x[idx] - s_scal[r][0]) * s_scal[r][1] * lg[k] + lb[k];
    }
    __syncthreads();

    float acc[ROWS];
#pragma unroll
    for (int r = 0; r < ROWS; ++r) acc[r] = 0.0f;
    if (tid < SPH) {
        const float* Wc = w1 + tid;
        for (int k = 0; k < SPD; k += 4) {
            const float w0 = Wc[(k + 0) * SPH];
            const float wv1 = Wc[(k + 1) * SPH];
            const float wv2 = Wc[(k + 2) * SPH];
            const float wv3 = Wc[(k + 3) * SPH];
#pragma unroll
            for (int r = 0; r < ROWS; ++r) {
                const float4 x4 = *reinterpret_cast<const float4*>(&s_x[r * SPD + k]);
                acc[r] += x4.x * w0 + x4.y * wv1 + x4.z * wv2 + x4.w * wv3;
            }
        }
    }
    const float bb = (tid < SPH) ? b1[tid] : 0.0f;
    const float wo = (tid < SPH) ? w2[tid] : 0.0f;
    const int wave = tid >> 6;
#pragma unroll
    for (int r = 0; r < ROWS; ++r) {
        float p = (tid < SPH) ? fmaxf(acc[r] + bb, 0.0f) * wo : 0.0f;
        p = wave_red_sum(p);
        if ((tid & 63) == 0) s_red[r][wave] = p;
    }
    __syncthreads();
    if (tid < ROWS) dspec[row0 + tid] = s_red[tid][0] + s_red[tid][1] + b2[0];
}

// ---------------------------------------------------------------------------
// k_conf: build conf_in (278), LN, 278->69 relu, dot, sigmoid, final output
// blockDim 128, ROWS=16.  LDS stride 280 for 16B alignment.
// ---------------------------------------------------------------------------
__global__ __launch_bounds__(128) void k_conf(
    const float* __restrict__ h_base, const float* __restrict__ z_top,
    const float* __restrict__ gstats,
    const float* __restrict__ yb, const float* __restrict__ dsafe,
    const float* __restrict__ dspec,
    const float* __restrict__ lg, const float* __restrict__ lb,
    const float* __restrict__ w1, const float* __restrict__ b1,
    const float* __restrict__ w2, const float* __restrict__ b2,
    float* __restrict__ out)
{
    constexpr int ROWS = 16;
    constexpr int STR = 280;
    __shared__ __align__(16) float s_x[ROWS * STR];
    __shared__ float s_scal[ROWS][2];
    __shared__ float s_red[ROWS][2];
    const int tid = threadIdx.x;
    const long row0 = (long)blockIdx.x * ROWS;

    for (int idx = tid; idx < ROWS * 64; idx += 128) {
        int r = idx >> 6, q = idx & 63;
        *reinterpret_cast<float4*>(&s_x[r * STR + q * 4]) =
            *reinterpret_cast<const float4*>(&h_base[(row0 + r) * 256 + q * 4]);
    }
    for (int idx = tid; idx < ROWS * 22; idx += 128) {
        int r = idx / 22, j = idx - r * 22;
        const long row = row0 + r;
        float v;
        if (j == 0)      v = yb[row];
        else if (j <= 3) v = gstats[row * 4 + (j - 1)];
        else if (j <= 19) v = z_top[row * TS + (j - 4)];
        else if (j == 20) v = fabsf(dsafe[row]);
        else              v = fabsf(dspec[row]);
        s_x[r * STR + 256 + j] = v;
    }
    __syncthreads();
    {
        const int r = tid >> 3, l8 = tid & 7;
        float sum = 0.0f;
#pragma unroll
        for (int i = 0; i < 35; ++i) { int k = l8 + 8 * i; if (k < CD) sum += s_x[r * STR + k]; }
        for (int m = 4; m; m >>= 1) sum += __shfl_xor(sum, m);
        const float mu = sum * (1.0f / (float)CD);
        float var = 0.0f;
#pragma unroll
        for (int i = 0; i < 35; ++i) { int k = l8 + 8 * i; if (k < CD) { float d = s_x[r * STR + k] - mu; var += d * d; } }
        for (int m = 4; m; m >>= 1) var += __shfl_xor(var, m);
        if (l8 == 0) { s_scal[r][0] = mu; s_scal[r][1] = rsqrtf(var * (1.0f / (float)CD) + 1e-5f); }
    }
    __syncthreads();
    for (int idx = tid; idx < ROWS * CD; idx += 128) {
        int r = idx / CD, k = idx - r * CD;
        s_x[r * STR + k] = (s_x[r * STR + k] - s_scal[r][0]) * s_scal[r][1] * lg[k] + lb[k];
    }
    __syncthreads();

    float acc[ROWS];
#pragma unroll
    for (int r = 0; r < ROWS; ++r) acc[r] = 0.0f;
    if (tid < CH) {
        const float* Wc = w1 + tid;
        for (int k = 0; k < CD; k += 2) {
            const float w0 = Wc[(k + 0) * CH];
            const float wv1 = Wc[(k + 1) * CH];
#pragma unroll
            for (int r = 0; r < ROWS; ++r) {
                const float2 x2 = *reinterpret_cast<const float2*>(&s_x[r * STR + k]);
                acc[r] += x2.x * w0 + x2.y * wv1;
            }
        }
    }
    const float bb = (tid < CH) ? b1[tid] : 0.0f;
    const float wo = (tid < CH) ? w2[tid] : 0.0f;
    const int wave = tid >> 6;
#pragma unroll
    for (int r = 0; r < ROWS; ++r) {
        float p = (tid < CH) ? fmaxf(acc[r] + bb, 0.0f) * wo : 0.0f;
        p = wave_red_sum(p);
        if ((tid & 63) == 0) s_red[r][wave] = p;
    }
    __syncthreads();
    if (tid < ROWS) {
        const long row = row0 + tid;
        const float gamma = 1.0f / (1.0f + expf(-(s_red[tid][0] + s_red[tid][1] + b2[0])));
        out[row] = yb[row] + dsafe[row] + gamma * dspec[row];
    }
}

// ---------------------------------------------------------------------------
extern "C" void kernel_launch(void* const* d_in, const int* in_sizes, int n_in,
                              void* d_out, int out_size, void* d_ws, size_t ws_size,
                              hipStream_t stream)
{
    const float* x_num   = (const float*)d_in[0];
    const float* center  = (const float*)d_in[1];
    const float* scale   = (const float*)d_in[2];
    const float* qs      = (const float*)d_in[3];
    const float* stem_w1 = (const float*)d_in[4];
    const float* stem_b1 = (const float*)d_in[5];
    const float* stem_w2 = (const float*)d_in[6];
    const float* stem_b2 = (const float*)d_in[7];
    const float* stem_w3 = (const float*)d_in[8];
    const float* stem_b3 = (const float*)d_in[9];
    const float* gate_w1 = (const float*)d_in[10];
    const float* gate_b1 = (const float*)d_in[11];
    const float* gate_w2 = (const float*)d_in[12];
    const float* gate_b2 = (const float*)d_in[13];
    const float* bb_w    = (const float*)d_in[14];
    const float* bb_b    = (const float*)d_in[15];
    const float* base_w  = (const float*)d_in[16];
    const float* base_b  = (const float*)d_in[17];
    const float* safe_lg = (const float*)d_in[18];
    const float* safe_lb = (const float*)d_in[19];
    const float* safe_w1 = (const float*)d_in[20];
    const float* safe_b1 = (const float*)d_in[21];
    const float* safe_w2 = (const float*)d_in[22];
    const float* safe_b2 = (const float*)d_in[23];
    const float* top_w1  = (const float*)d_in[24];
    const float* top_b1  = (const float*)d_in[25];
    const float* top_w2  = (const float*)d_in[26];
    const float* top_b2  = (const float*)d_in[27];
    const float* spec_lg = (const float*)d_in[28];
    const float* spec_lb = (const float*)d_in[29];
    const float* spec_w1 = (const float*)d_in[30];
    const float* spec_b1 = (const float*)d_in[31];
    const float* spec_w2 = (const float*)d_in[32];
    const float* spec_b2 = (const float*)d_in[33];
    const float* conf_lg = (const float*)d_in[34];
    const float* conf_lb = (const float*)d_in[35];
    const float* conf_w1 = (const float*)d_in[36];
    const float* conf_b1 = (const float*)d_in[37];
    const float* conf_w2 = (const float*)d_in[38];
    const float* conf_b2 = (const float*)d_in[39];

    float* ws    = (float*)d_ws;
    float* x_cal = ws;                       // B*256
    float* g_h   = x_cal + (long)B * 256;    // B*128
    float* g     = g_h   + (long)B * 128;    // B*256
    float* h_b   = g     + (long)B * 256;    // B*256
    float* z_top = h_b   + (long)B * 256;    // B*16
    float* gstat = z_top + (long)B * 16;     // B*4
    float* yb    = gstat + (long)B * 4;      // B
    float* dsafe = yb    + (long)B;          // B
    float* dspec = dsafe + (long)B;          // B
    float* out   = (float*)d_out;

    k_calib<<<B, 256, 0, stream>>>(x_num, center, scale, qs,
                                   stem_w1, stem_b1, stem_w2, stem_b2, stem_w3, stem_b3,
                                   x_cal);
    k_linear2<256, 128, 0, false><<<B / 16, 128, 0, stream>>>(x_cal, nullptr, gate_w1, gate_b1, g_h);
    k_linear2<128, 256, 1, false><<<B / 16, 256, 0, stream>>>(g_h, nullptr, gate_w2, gate_b2, g);
    k_topk<<<B, 64, 0, stream>>>(g, x_cal, top_w1, top_b1, top_w2, top_b2, z_top, gstat);
    k_linear2<256, 256, 0, true><<<B / 16, 256, 0, stream>>>(x_cal, g, bb_w, bb_b, h_b);
    k_safe<<<B / 16, 128, 0, stream>>>(h_b, base_w, base_b,
                                       safe_lg, safe_lb, safe_w1, safe_b1, safe_w2, safe_b2,
                                       yb, dsafe);
    k_spec<<<B / 16, 128, 0, stream>>>(h_b, z_top,
                                       spec_lg, spec_lb, spec_w1, spec_b1, spec_w2, spec_b2,
                                       dspec);
    k_conf<<<B / 16, 128, 0, stream>>>(h_b, z_top, gstat, yb, dsafe, dspec,
                                       conf_lg, conf_lb, conf_w1, conf_b1, conf_w2, conf_b2,
                                       out);
}

// Round 4
// 462.159 us; speedup vs baseline: 1.2249x; 1.1373x over previous
//
#include <hip/hip_runtime.h>
#include <math.h>

static constexpr int B  = 16384;
static constexpr int F  = 256;
static constexpr int NQ = 2048;
static constexpr int TS = 16;
static constexpr int KTOP = 8;
static constexpr int SPD = 272;   // 256 + 16
static constexpr int SPH = 68;
static constexpr int CD  = 278;   // 256+1+3+16+2
static constexpr int CH  = 69;

typedef __attribute__((ext_vector_type(8))) short bf16x8;
typedef __attribute__((ext_vector_type(4))) float f32x4;

__device__ inline short f2bf(float f) {
    unsigned u = __builtin_bit_cast(unsigned, f);
    unsigned r = (u + 0x7FFF + ((u >> 16) & 1)) >> 16;   // RNE
    return (short)r;
}

__device__ inline float fast_tanh(float o) {
    o = fminf(fmaxf(o, -15.0f), 15.0f);
    float e = __expf(2.0f * o);
    return (e - 1.0f) / (e + 1.0f);
}

// ---------------------------------------------------------------------------
// k_prep: transpose+convert 3 weight matrices to bf16 W^T[N][K]
// blocks: [0,32) w1 (K256,N128); [32,64) w2 (K128,N256); [64,128) bb (256,256)
// ---------------------------------------------------------------------------
__global__ __launch_bounds__(1024) void k_prep(
    const float* __restrict__ w1, const float* __restrict__ w2,
    const float* __restrict__ w3,
    short* __restrict__ t1, short* __restrict__ t2, short* __restrict__ t3)
{
    __shared__ float tile[32][33];
    const int bid = blockIdx.x;
    const float* W; short* T; int K, N, kt, nt;
    if (bid < 32)      { W = w1; T = t1; K = 256; N = 128; kt = bid >> 2;        nt = bid & 3; }
    else if (bid < 64) { W = w2; T = t2; K = 128; N = 256; kt = (bid - 32) >> 3; nt = (bid - 32) & 7; }
    else               { W = w3; T = t3; K = 256; N = 256; kt = (bid - 64) >> 3; nt = (bid - 64) & 7; }
    const int tx = threadIdx.x & 31, ty = threadIdx.x >> 5;
    tile[ty][tx] = W[(kt * 32 + ty) * N + nt * 32 + tx];
    __syncthreads();
    T[(nt * 32 + ty) * K + kt * 32 + tx] = f2bf(tile[tx][ty]);
}

// ---------------------------------------------------------------------------
// k_calib2: 2 rows per block, interleaved binary searches + stem MLP.
// Fixed 12-iteration search; index clamped (never reads qs[NQ]) and update
// guarded by lo<hi (converged searches are no-ops) — the R3 OOB fix.
// ---------------------------------------------------------------------------
__global__ __launch_bounds__(256) void k_calib2(
    const float* __restrict__ x_num, const float* __restrict__ center,
    const float* __restrict__ scale, const float* __restrict__ qs,
    const float* __restrict__ sw1, const float* __restrict__ sb1,
    const float* __restrict__ sw2, const float* __restrict__ sb2,
    const float* __restrict__ sw3, const float* __restrict__ sb3,
    float* __restrict__ x_cal)
{
    __shared__ float s_w1[48], s_b1[16], s_w2[256], s_b2[16], s_w3[16];
    const int tid = threadIdx.x;
    if (tid < 48) s_w1[tid] = sw1[tid];
    if (tid < 16) { s_b1[tid] = sb1[tid]; s_b2[tid] = sb2[tid]; s_w3[tid] = sw3[tid]; }
    s_w2[tid] = sw2[tid];
    __syncthreads();

    const long b0 = (long)blockIdx.x * 2;
    const int f = tid;
    const float xa = x_num[b0 * F + f];
    const float xb = x_num[(b0 + 1) * F + f];
    const float c = center[f], sc = scale[f];
    const float xra = (xa - c) / sc;
    const float xrb = (xb - c) / sc;

    int loa = 0, hia = NQ, lob = 0, hib = NQ;
#pragma unroll 1
    for (int it = 0; it < 12; ++it) {
        const int ma = (loa + hia) >> 1;
        const int mb = (lob + hib) >> 1;
        const int ca = ma < (NQ - 1) ? ma : (NQ - 1);   // clamp: never read row NQ
        const int cb = mb < (NQ - 1) ? mb : (NQ - 1);
        const float qa = qs[(long)ca * F + f];
        const float qb = qs[(long)cb * F + f];
        if (loa < hia) { if (qa < xa) loa = ma + 1; else hia = ma; }
        if (lob < hib) { if (qb < xb) lob = mb + 1; else hib = mb; }
    }
    const float xqa = fminf((float)loa * (1.0f / (float)(NQ - 1)), 1.0f);
    const float xqb = fminf((float)lob * (1.0f / (float)(NQ - 1)), 1.0f);

    float h1a[16], h1b[16];
#pragma unroll
    for (int j = 0; j < 16; ++j) {
        const float w0 = s_w1[j], w1 = s_w1[16 + j], w2 = s_w1[32 + j], bb = s_b1[j];
        h1a[j] = fmaxf(bb + xa * w0 + xra * w1 + xqa * w2, 0.0f);
        h1b[j] = fmaxf(bb + xb * w0 + xrb * w1 + xqb * w2, 0.0f);
    }
    float h2a[16], h2b[16];
#pragma unroll
    for (int j = 0; j < 16; ++j) { h2a[j] = s_b2[j]; h2b[j] = s_b2[j]; }
#pragma unroll 4
    for (int i = 0; i < 16; ++i) {
        float wv[16];
        const float4* wr = reinterpret_cast<const float4*>(&s_w2[i * 16]);
        *reinterpret_cast<float4*>(&wv[0])  = wr[0];
        *reinterpret_cast<float4*>(&wv[4])  = wr[1];
        *reinterpret_cast<float4*>(&wv[8])  = wr[2];
        *reinterpret_cast<float4*>(&wv[12]) = wr[3];
        const float a = h1a[i], bb = h1b[i];
#pragma unroll
        for (int j = 0; j < 16; ++j) { h2a[j] += a * wv[j]; h2b[j] += bb * wv[j]; }
    }
    float w3v[16];
    {
        const float4* wr = reinterpret_cast<const float4*>(&s_w3[0]);
        *reinterpret_cast<float4*>(&w3v[0])  = wr[0];
        *reinterpret_cast<float4*>(&w3v[4])  = wr[1];
        *reinterpret_cast<float4*>(&w3v[8])  = wr[2];
        *reinterpret_cast<float4*>(&w3v[12]) = wr[3];
    }
    float oa = sb3[0], ob = sb3[0];
#pragma unroll
    for (int j = 0; j < 16; ++j) {
        oa += fmaxf(h2a[j], 0.0f) * w3v[j];
        ob += fmaxf(h2b[j], 0.0f) * w3v[j];
    }
    x_cal[b0 * F + f]       = xa + 0.1f * fast_tanh(oa);
    x_cal[(b0 + 1) * F + f] = xb + 0.1f * fast_tanh(ob);
}

// ---------------------------------------------------------------------------
// k_mfma: C[M x N] = act(A[M x K] (*mul) @ W[K x N] + bias)
// Wt is bf16 W^T [N][K].  Wave tile 16x64 (4 n-tiles), block = 2x2 waves = 32x128.
// grid = (M/32, N/128).  AMODE: 0 = A fp32, 1 = A fp32 * mul fp32.
// ACT: 0 relu, 1 sigmoid.
// ---------------------------------------------------------------------------
template <int K, int N, int ACT, int AMODE>
__global__ __launch_bounds__(256) void k_mfma(
    const float* __restrict__ A, const float* __restrict__ mul,
    const short* __restrict__ Wt, const float* __restrict__ bias,
    float* __restrict__ out)
{
    const int tid = threadIdx.x;
    const int wave = tid >> 6;
    const int lane = tid & 63;
    const int sub = lane & 15, quad = lane >> 4;
    const int wm = wave & 1, wn = wave >> 1;
    const long mrow = (long)blockIdx.x * 32 + wm * 16 + sub;     // A row this lane loads
    const int n_base = blockIdx.y * 128 + wn * 64;

    f32x4 acc0 = {0,0,0,0}, acc1 = {0,0,0,0}, acc2 = {0,0,0,0}, acc3 = {0,0,0,0};

#pragma unroll
    for (int k0 = 0; k0 < K; k0 += 32) {
        const float* ap = A + mrow * K + k0 + quad * 8;
        float av[8];
        *reinterpret_cast<float4*>(&av[0]) = *reinterpret_cast<const float4*>(ap);
        *reinterpret_cast<float4*>(&av[4]) = *reinterpret_cast<const float4*>(ap + 4);
        if (AMODE == 1) {
            const float* mp = mul + mrow * K + k0 + quad * 8;
            float mv[8];
            *reinterpret_cast<float4*>(&mv[0]) = *reinterpret_cast<const float4*>(mp);
            *reinterpret_cast<float4*>(&mv[4]) = *reinterpret_cast<const float4*>(mp + 4);
#pragma unroll
            for (int j = 0; j < 8; ++j) av[j] *= mv[j];
        }
        bf16x8 afrag;
#pragma unroll
        for (int j = 0; j < 8; ++j) afrag[j] = f2bf(av[j]);

        const short* bp = Wt + (long)(n_base + sub) * K + k0 + quad * 8;
        const bf16x8 b0 = *reinterpret_cast<const bf16x8*>(bp);
        const bf16x8 b1 = *reinterpret_cast<const bf16x8*>(bp + 16 * K);
        const bf16x8 b2 = *reinterpret_cast<const bf16x8*>(bp + 32 * K);
        const bf16x8 b3 = *reinterpret_cast<const bf16x8*>(bp + 48 * K);
        acc0 = __builtin_amdgcn_mfma_f32_16x16x32_bf16(afrag, b0, acc0, 0, 0, 0);
        acc1 = __builtin_amdgcn_mfma_f32_16x16x32_bf16(afrag, b1, acc1, 0, 0, 0);
        acc2 = __builtin_amdgcn_mfma_f32_16x16x32_bf16(afrag, b2, acc2, 0, 0, 0);
        acc3 = __builtin_amdgcn_mfma_f32_16x16x32_bf16(afrag, b3, acc3, 0, 0, 0);
    }

    // D: row = quad*4 + r, col = t*16 + sub
    const long row_out = (long)blockIdx.x * 32 + wm * 16 + quad * 4;
    const f32x4 accs[4] = {acc0, acc1, acc2, acc3};
#pragma unroll
    for (int t = 0; t < 4; ++t) {
        const int col = n_base + t * 16 + sub;
        const float bb = bias[col];
#pragma unroll
        for (int r = 0; r < 4; ++r) {
            float v = accs[t][r] + bb;
            if (ACT == 0) v = fmaxf(v, 0.0f);
            else          v = 1.0f / (1.0f + __expf(-v));
            out[(row_out + r) * N + col] = v;
        }
    }
}

// ---------------------------------------------------------------------------
// k_topk (unchanged)
// ---------------------------------------------------------------------------
__global__ __launch_bounds__(64) void k_topk(
    const float* __restrict__ g, const float* __restrict__ x_cal,
    const float* __restrict__ tw1, const float* __restrict__ tb1,
    const float* __restrict__ tw2, const float* __restrict__ tb2,
    float* __restrict__ z_top, float* __restrict__ stats)
{
    __shared__ float s_hm[16];
    const int b = blockIdx.x;
    const int lane = threadIdx.x;
    const long base = (long)b * F;

    float gv[4];
#pragma unroll
    for (int i = 0; i < 4; ++i) gv[i] = g[base + lane + 64 * i];

    float s = gv[0] + gv[1] + gv[2] + gv[3];
    float mx = fmaxf(fmaxf(gv[0], gv[1]), fmaxf(gv[2], gv[3]));
    for (int m = 32; m; m >>= 1) {
        s  += __shfl_xor(s, m);
        mx  = fmaxf(mx, __shfl_xor(mx, m));
    }
    const float mean = s * (1.0f / 256.0f);
    float vs = 0.0f;
#pragma unroll
    for (int i = 0; i < 4; ++i) { float d = gv[i] - mean; vs += d * d; }
    for (int m = 32; m; m >>= 1) vs += __shfl_xor(vs, m);
    const float stdv = sqrtf(vs * (1.0f / 256.0f));

    float cur[4]; int curi[4];
#pragma unroll
    for (int i = 0; i < 4; ++i) { cur[i] = gv[i]; curi[i] = lane + 64 * i; }
    float tv[KTOP]; int ti[KTOP]; float vsum = 0.0f;
    for (int r = 0; r < KTOP; ++r) {
        float bv = cur[0]; int bi = curi[0];
#pragma unroll
        for (int i = 1; i < 4; ++i)
            if (cur[i] > bv || (cur[i] == bv && curi[i] < bi)) { bv = cur[i]; bi = curi[i]; }
        for (int m = 32; m; m >>= 1) {
            float ov = __shfl_xor(bv, m);
            int   oi = __shfl_xor(bi, m);
            if (ov > bv || (ov == bv && oi < bi)) { bv = ov; bi = oi; }
        }
        tv[r] = bv; ti[r] = bi; vsum += bv;
#pragma unroll
        for (int i = 0; i < 4; ++i) if (curi[i] == bi) cur[i] = -INFINITY;
    }
    const float denom = 1.0f / (vsum + 1e-6f);

    if (lane < 16) {
        float hm = 0.0f;
        for (int k = 0; k < KTOP; ++k) {
            const float xk = x_cal[base + ti[k]];
            const float xw = xk * (tv[k] * denom);
            hm += fmaxf(xw * tw1[lane] + tb1[lane], 0.0f);
        }
        s_hm[lane] = hm * (1.0f / (float)KTOP);
    }
    __syncthreads();
    if (lane < 16) {
        float z = tb2[lane];
#pragma unroll
        for (int j = 0; j < 16; ++j) z += s_hm[j] * tw2[j * 16 + lane];
        z_top[(long)b * TS + lane] = z;
    }
    if (lane == 0) {
        stats[(long)b * 4 + 0] = mean;
        stats[(long)b * 4 + 1] = mx;
        stats[(long)b * 4 + 2] = stdv;
    }
}

__device__ inline float wave_red_sum(float v) {
    for (int m = 32; m; m >>= 1) v += __shfl_xor(v, m);
    return v;
}

// ---------------------------------------------------------------------------
// k_safe (unchanged)
// ---------------------------------------------------------------------------
__global__ __launch_bounds__(128) void k_safe(
    const float* __restrict__ h_base,
    const float* __restrict__ base_w, const float* __restrict__ base_b,
    const float* __restrict__ lg, const float* __restrict__ lb,
    const float* __restrict__ w1, const float* __restrict__ b1,
    const float* __restrict__ w2, const float* __restrict__ b2,
    float* __restrict__ yb, float* __restrict__ dsafe)
{
    constexpr int ROWS = 16;
    __shared__ __align__(16) float s_h[ROWS * 256];
    __shared__ float s_scal[ROWS][2];
    __shared__ float s_red[ROWS][2];
    const int tid = threadIdx.x;
    const long row0 = (long)blockIdx.x * ROWS;

    const float4* in4 = reinterpret_cast<const float4*>(h_base + row0 * 256);
    float4* s4 = reinterpret_cast<float4*>(s_h);
    for (int idx = tid; idx < ROWS * 64; idx += 128) s4[idx] = in4[idx];
    __syncthreads();

    {
        const int r = tid >> 3, l8 = tid & 7;
        float sum = 0.0f, ysum = 0.0f;
#pragma unroll
        for (int i = 0; i < 32; ++i) {
            int k = l8 + 8 * i;
            float v = s_h[r * 256 + k];
            sum += v; ysum += v * base_w[k];
        }
        for (int m = 4; m; m >>= 1) { sum += __shfl_xor(sum, m); ysum += __shfl_xor(ysum, m); }
        const float mu = sum * (1.0f / 256.0f);
        float var = 0.0f;
#pragma unroll
        for (int i = 0; i < 32; ++i) {
            int k = l8 + 8 * i;
            float d = s_h[r * 256 + k] - mu; var += d * d;
        }
        for (int m = 4; m; m >>= 1) var += __shfl_xor(var, m);
        if (l8 == 0) {
            s_scal[r][0] = mu;
            s_scal[r][1] = rsqrtf(var * (1.0f / 256.0f) + 1e-5f);
            yb[row0 + r] = ysum + base_b[0];
        }
    }
    __syncthreads();
    for (int idx = tid; idx < ROWS * 256; idx += 128) {
        int r = idx >> 8, k = idx & 255;
        s_h[idx] = (s_h[idx] - s_scal[r][0]) * s_scal[r][1] * lg[k] + lb[k];
    }
    __syncthreads();

    float acc[ROWS];
#pragma unroll
    for (int r = 0; r < ROWS; ++r) acc[r] = 0.0f;
    const float* Wc = w1 + tid;
    for (int k = 0; k < 256; k += 4) {
        const float w0 = Wc[(k + 0) * 128];
        const float wv1 = Wc[(k + 1) * 128];
        const float wv2 = Wc[(k + 2) * 128];
        const float wv3 = Wc[(k + 3) * 128];
#pragma unroll
        for (int r = 0; r < ROWS; ++r) {
            const float4 x4 = *reinterpret_cast<const float4*>(&s_h[r * 256 + k]);
            acc[r] += x4.x * w0 + x4.y * wv1 + x4.z * wv2 + x4.w * wv3;
        }
    }
    const float bb = b1[tid], wo = w2[tid];
    const int wave = tid >> 6;
#pragma unroll
    for (int r = 0; r < ROWS; ++r) {
        float p = fmaxf(acc[r] + bb, 0.0f) * wo;
        p = wave_red_sum(p);
        if ((tid & 63) == 0) s_red[r][wave] = p;
    }
    __syncthreads();
    if (tid < ROWS) dsafe[row0 + tid] = s_red[tid][0] + s_red[tid][1] + b2[0];
}

// ---------------------------------------------------------------------------
// k_spec (unchanged)
// ---------------------------------------------------------------------------
__global__ __launch_bounds__(128) void k_spec(
    const float* __restrict__ h_base, const float* __restrict__ z_top,
    const float* __restrict__ lg, const float* __restrict__ lb,
    const float* __restrict__ w1, const float* __restrict__ b1,
    const float* __restrict__ w2, const float* __restrict__ b2,
    float* __restrict__ dspec)
{
    constexpr int ROWS = 16;
    __shared__ __align__(16) float s_x[ROWS * SPD];
    __shared__ float s_scal[ROWS][2];
    __shared__ float s_red[ROWS][2];
    const int tid = threadIdx.x;
    const long row0 = (long)blockIdx.x * ROWS;

    for (int idx = tid; idx < ROWS * 64; idx += 128) {
        int r = idx >> 6, q = idx & 63;
        *reinterpret_cast<float4*>(&s_x[r * SPD + q * 4]) =
            *reinterpret_cast<const float4*>(&h_base[(row0 + r) * 256 + q * 4]);
    }
    for (int idx = tid; idx < ROWS * TS; idx += 128) {
        int r = idx >> 4, j = idx & 15;
        s_x[r * SPD + 256 + j] = z_top[(row0 + r) * TS + j];
    }
    __syncthreads();
    {
        const int r = tid >> 3, l8 = tid & 7;
        float sum = 0.0f;
#pragma unroll
        for (int i = 0; i < 34; ++i) sum += s_x[r * SPD + l8 + 8 * i];
        for (int m = 4; m; m >>= 1) sum += __shfl_xor(sum, m);
        const float mu = sum * (1.0f / (float)SPD);
        float var = 0.0f;
#pragma unroll
        for (int i = 0; i < 34; ++i) { float d = s_x[r * SPD + l8 + 8 * i] - mu; var += d * d; }
        for (int m = 4; m; m >>= 1) var += __shfl_xor(var, m);
        if (l8 == 0) { s_scal[r][0] = mu; s_scal[r][1] = rsqrtf(var * (1.0f / (float)SPD) + 1e-5f); }
    }
    __syncthreads();
    for (int idx = tid; idx < ROWS * SPD; idx += 128) {
        int r = idx / SPD, k = idx - r * SPD;
        s_x[idx] = (s_x[idx] - s_scal[r][0]) * s_scal[r][1] * lg[k] + lb[k];
    }
    __syncthreads();

    float acc[ROWS];
#pragma unroll
    for (int r = 0; r < ROWS; ++r) acc[r] = 0.0f;
    if (tid < SPH) {
        const float* Wc = w1 + tid;
        for (int k = 0; k < SPD; k += 4) {
            const float w0 = Wc[(k + 0) * SPH];
            const float wv1 = Wc[(k + 1) * SPH];
            const float wv2 = Wc[(k + 2) * SPH];
            const float wv3 = Wc[(k + 3) * SPH];
#pragma unroll
            for (int r = 0; r < ROWS; ++r) {
                const float4 x4 = *reinterpret_cast<const float4*>(&s_x[r * SPD + k]);
                acc[r] += x4.x * w0 + x4.y * wv1 + x4.z * wv2 + x4.w * wv3;
            }
        }
    }
    const float bb = (tid < SPH) ? b1[tid] : 0.0f;
    const float wo = (tid < SPH) ? w2[tid] : 0.0f;
    const int wave = tid >> 6;
#pragma unroll
    for (int r = 0; r < ROWS; ++r) {
        float p = (tid < SPH) ? fmaxf(acc[r] + bb, 0.0f) * wo : 0.0f;
        p = wave_red_sum(p);
        if ((tid & 63) == 0) s_red[r][wave] = p;
    }
    __syncthreads();
    if (tid < ROWS) dspec[row0 + tid] = s_red[tid][0] + s_red[tid][1] + b2[0];
}

// ---------------------------------------------------------------------------
// k_conf (unchanged)
// ---------------------------------------------------------------------------
__global__ __launch_bounds__(128) void k_conf(
    const float* __restrict__ h_base, const float* __restrict__ z_top,
    const float* __restrict__ gstats,
    const float* __restrict__ yb, const float* __restrict__ dsafe,
    const float* __restrict__ dspec,
    const float* __restrict__ lg, const float* __restrict__ lb,
    const float* __restrict__ w1, const float* __restrict__ b1,
    const float* __restrict__ w2, const float* __restrict__ b2,
    float* __restrict__ out)
{
    constexpr int ROWS = 16;
    constexpr int STR = 280;
    __shared__ __align__(16) float s_x[ROWS * STR];
    __shared__ float s_scal[ROWS][2];
    __shared__ float s_red[ROWS][2];
    const int tid = threadIdx.x;
    const long row0 = (long)blockIdx.x * ROWS;

    for (int idx = tid; idx < ROWS * 64; idx += 128) {
        int r = idx >> 6, q = idx & 63;
        *reinterpret_cast<float4*>(&s_x[r * STR + q * 4]) =
            *reinterpret_cast<const float4*>(&h_base[(row0 + r) * 256 + q * 4]);
    }
    for (int idx = tid; idx < ROWS * 22; idx += 128) {
        int r = idx / 22, j = idx - r * 22;
        const long row = row0 + r;
        float v;
        if (j == 0)      v = yb[row];
        else if (j <= 3) v = gstats[row * 4 + (j - 1)];
        else if (j <= 19) v = z_top[row * TS + (j - 4)];
        else if (j == 20) v = fabsf(dsafe[row]);
        else              v = fabsf(dspec[row]);
        s_x[r * STR + 256 + j] = v;
    }
    __syncthreads();
    {
        const int r = tid >> 3, l8 = tid & 7;
        float sum = 0.0f;
#pragma unroll
        for (int i = 0; i < 35; ++i) { int k = l8 + 8 * i; if (k < CD) sum += s_x[r * STR + k]; }
        for (int m = 4; m; m >>= 1) sum += __shfl_xor(sum, m);
        const float mu = sum * (1.0f / (float)CD);
        float var = 0.0f;
#pragma unroll
        for (int i = 0; i < 35; ++i) { int k = l8 + 8 * i; if (k < CD) { float d = s_x[r * STR + k] - mu; var += d * d; } }
        for (int m = 4; m; m >>= 1) var += __shfl_xor(var, m);
        if (l8 == 0) { s_scal[r][0] = mu; s_scal[r][1] = rsqrtf(var * (1.0f / (float)CD) + 1e-5f); }
    }
    __syncthreads();
    for (int idx = tid; idx < ROWS * CD; idx += 128) {
        int r = idx / CD, k = idx - r * CD;
        s_x[r * STR + k] = (s_x[r * STR + k] - s_scal[r][0]) * s_scal[r][1] * lg[k] + lb[k];
    }
    __syncthreads();

    float acc[ROWS];
#pragma unroll
    for (int r = 0; r < ROWS; ++r) acc[r] = 0.0f;
    if (tid < CH) {
        const float* Wc = w1 + tid;
        for (int k = 0; k < CD; k += 2) {
            const float w0 = Wc[(k + 0) * CH];
            const float wv1 = Wc[(k + 1) * CH];
#pragma unroll
            for (int r = 0; r < ROWS; ++r) {
                const float2 x2 = *reinterpret_cast<const float2*>(&s_x[r * STR + k]);
                acc[r] += x2.x * w0 + x2.y * wv1;
            }
        }
    }
    const float bb = (tid < CH) ? b1[tid] : 0.0f;
    const float wo = (tid < CH) ? w2[tid] : 0.0f;
    const int wave = tid >> 6;
#pragma unroll
    for (int r = 0; r < ROWS; ++r) {
        float p = (tid < CH) ? fmaxf(acc[r] + bb, 0.0f) * wo : 0.0f;
        p = wave_red_sum(p);
        if ((tid & 63) == 0) s_red[r][wave] = p;
    }
    __syncthreads();
    if (tid < ROWS) {
        const long row = row0 + tid;
        const float gamma = 1.0f / (1.0f + expf(-(s_red[tid][0] + s_red[tid][1] + b2[0])));
        out[row] = yb[row] + dsafe[row] + gamma * dspec[row];
    }
}

// ---------------------------------------------------------------------------
extern "C" void kernel_launch(void* const* d_in, const int* in_sizes, int n_in,
                              void* d_out, int out_size, void* d_ws, size_t ws_size,
                              hipStream_t stream)
{
    const float* x_num   = (const float*)d_in[0];
    const float* center  = (const float*)d_in[1];
    const float* scale   = (const float*)d_in[2];
    const float* qs      = (const float*)d_in[3];
    const float* stem_w1 = (const float*)d_in[4];
    const float* stem_b1 = (const float*)d_in[5];
    const float* stem_w2 = (const float*)d_in[6];
    const float* stem_b2 = (const float*)d_in[7];
    const float* stem_w3 = (const float*)d_in[8];
    const float* stem_b3 = (const float*)d_in[9];
    const float* gate_w1 = (const float*)d_in[10];
    const float* gate_b1 = (const float*)d_in[11];
    const float* gate_w2 = (const float*)d_in[12];
    const float* gate_b2 = (const float*)d_in[13];
    const float* bb_w    = (const float*)d_in[14];
    const float* bb_b    = (const float*)d_in[15];
    const float* base_w  = (const float*)d_in[16];
    const float* base_b  = (const float*)d_in[17];
    const float* safe_lg = (const float*)d_in[18];
    const float* safe_lb = (const float*)d_in[19];
    const float* safe_w1 = (const float*)d_in[20];
    const float* safe_b1 = (const float*)d_in[21];
    const float* safe_w2 = (const float*)d_in[22];
    const float* safe_b2 = (const float*)d_in[23];
    const float* top_w1  = (const float*)d_in[24];
    const float* top_b1  = (const float*)d_in[25];
    const float* top_w2  = (const float*)d_in[26];
    const float* top_b2  = (const float*)d_in[27];
    const float* spec_lg = (const float*)d_in[28];
    const float* spec_lb = (const float*)d_in[29];
    const float* spec_w1 = (const float*)d_in[30];
    const float* spec_b1 = (const float*)d_in[31];
    const float* spec_w2 = (const float*)d_in[32];
    const float* spec_b2 = (const float*)d_in[33];
    const float* conf_lg = (const float*)d_in[34];
    const float* conf_lb = (const float*)d_in[35];
    const float* conf_w1 = (const float*)d_in[36];
    const float* conf_b1 = (const float*)d_in[37];
    const float* conf_w2 = (const float*)d_in[38];
    const float* conf_b2 = (const float*)d_in[39];

    float* ws    = (float*)d_ws;
    float* x_cal = ws;                       // B*256
    float* g_h   = x_cal + (long)B * 256;    // B*128
    float* g     = g_h   + (long)B * 128;    // B*256
    float* h_b   = g     + (long)B * 256;    // B*256
    float* z_top = h_b   + (long)B * 256;    // B*16
    float* gstat = z_top + (long)B * 16;     // B*4
    float* yb    = gstat + (long)B * 4;      // B
    float* dsafe = yb    + (long)B;          // B
    float* dspec = dsafe + (long)B;          // B
    short* w1t   = (short*)(dspec + (long)B); // 128*256 bf16 (gate_w1^T)
    short* w2t   = w1t + 128 * 256;           // 256*128 bf16 (gate_w2^T)
    short* bbt   = w2t + 256 * 128;           // 256*256 bf16 (bb_w^T)
    float* out   = (float*)d_out;

    k_prep<<<128, 1024, 0, stream>>>(gate_w1, gate_w2, bb_w, w1t, w2t, bbt);
    k_calib2<<<B / 2, 256, 0, stream>>>(x_num, center, scale, qs,
                                        stem_w1, stem_b1, stem_w2, stem_b2, stem_w3, stem_b3,
                                        x_cal);
    k_mfma<256, 128, 0, 0><<<dim3(B / 32, 1), 256, 0, stream>>>(x_cal, nullptr, w1t, gate_b1, g_h);
    k_mfma<128, 256, 1, 0><<<dim3(B / 32, 2), 256, 0, stream>>>(g_h, nullptr, w2t, gate_b2, g);
    k_topk<<<B, 64, 0, stream>>>(g, x_cal, top_w1, top_b1, top_w2, top_b2, z_top, gstat);
    k_mfma<256, 256, 0, 1><<<dim3(B / 32, 2), 256, 0, stream>>>(x_cal, g, bbt, bb_b, h_b);
    k_safe<<<B / 16, 128, 0, stream>>>(h_b, base_w, base_b,
                                       safe_lg, safe_lb, safe_w1, safe_b1, safe_w2, safe_b2,
                                       yb, dsafe);
    k_spec<<<B / 16, 128, 0, stream>>>(h_b, z_top,
                                       spec_lg, spec_lb, spec_w1, spec_b1, spec_w2, spec_b2,
                                       dspec);
    k_conf<<<B / 16, 128, 0, stream>>>(h_b, z_top, gstat, yb, dsafe, dspec,
                                       conf_lg, conf_lb, conf_w1, conf_b1, conf_w2, conf_b2,
                                       out);
}

// Round 5
// 388.277 us; speedup vs baseline: 1.4580x; 1.1903x over previous
//
#include <hip/hip_runtime.h>
#include <math.h>

static constexpr int B  = 16384;
static constexpr int F  = 256;
static constexpr int NQ = 2048;
static constexpr int TS = 16;
static constexpr int KTOP = 8;
static constexpr int SPD = 272;   // 256 + 16
static constexpr int SPH = 68;
static constexpr int CD  = 278;   // 256+1+3+16+2
static constexpr int CH  = 69;

typedef __attribute__((ext_vector_type(8))) short bf16x8;
typedef __attribute__((ext_vector_type(4))) float f32x4;

__device__ inline short f2bf(float f) {
    unsigned u = __builtin_bit_cast(unsigned, f);
    unsigned r = (u + 0x7FFF + ((u >> 16) & 1)) >> 16;   // RNE
    return (short)r;
}

__device__ inline float fast_tanh(float o) {
    o = fminf(fmaxf(o, -15.0f), 15.0f);
    float e = __expf(2.0f * o);
    return (e - 1.0f) / (e + 1.0f);
}

// ---------------------------------------------------------------------------
// k_prepall: one kernel producing all bf16 W^T buffers (padded) + qs transpose.
// Ranges (flat idx):
//  [0,32768)        w1t   [128][256]  from gate_w1 (256,128)
//  [32768,65536)    w2t   [256][128]  from gate_w2 (128,256)
//  [65536,131072)   bbt   [256][256]  from bb_w    (256,256)
//  [131072,163840)  sw1t  [128][256]  from safe_w1 (256,128)
//  [163840,200704)  spw1t [128][288]  from spec_w1 (272,68)   zero-padded
//  [200704,237568)  cfw1t [128][288]  from conf_w1 (278,69)   zero-padded
//  [237568,761856)  qs_t  [256][2048] from qs      (2048,256)
// ---------------------------------------------------------------------------
__device__ inline void prep_one(const float* W, short* T, int local,
                                int K, int N, int KP) {
    const int n = local / KP, k = local - n * KP;
    T[local] = (k < K && n < N) ? f2bf(W[k * N + n]) : (short)0;
}

__global__ __launch_bounds__(256) void k_prepall(
    const float* __restrict__ gate_w1, const float* __restrict__ gate_w2,
    const float* __restrict__ bb_w,    const float* __restrict__ safe_w1,
    const float* __restrict__ spec_w1, const float* __restrict__ conf_w1,
    const float* __restrict__ qs,
    short* __restrict__ w1t, short* __restrict__ w2t, short* __restrict__ bbt,
    short* __restrict__ sw1t, short* __restrict__ spw1t, short* __restrict__ cfw1t,
    float* __restrict__ qs_t)
{
    const int idx = blockIdx.x * 256 + threadIdx.x;
    if (idx < 32768)       prep_one(gate_w1, w1t,  idx,           256, 128, 256);
    else if (idx < 65536)  prep_one(gate_w2, w2t,  idx - 32768,   128, 256, 128);
    else if (idx < 131072) prep_one(bb_w,    bbt,  idx - 65536,   256, 256, 256);
    else if (idx < 163840) prep_one(safe_w1, sw1t, idx - 131072,  256, 128, 256);
    else if (idx < 200704) prep_one(spec_w1, spw1t, idx - 163840, 272, 68, 288);
    else if (idx < 237568) prep_one(conf_w1, cfw1t, idx - 200704, 278, 69, 288);
    else if (idx < 761856) {
        const int local = idx - 237568;
        const int f = local >> 11, q = local & 2047;
        qs_t[local] = qs[q * 256 + f];
    }
}

// ---------------------------------------------------------------------------
// k_calib3: 4 rows per block. Coarse 16-way search via LDS-cached subsampled
// quantiles (15 probes, count-based), then 7 fixed binary iterations in the
// transposed table qs_t[f][2048] (per-lane contiguous column). Then stem MLP.
// ---------------------------------------------------------------------------
__global__ __launch_bounds__(256) void k_calib3(
    const float* __restrict__ x_num, const float* __restrict__ center,
    const float* __restrict__ scale, const float* __restrict__ qs,
    const float* __restrict__ qs_t,
    const float* __restrict__ sw1, const float* __restrict__ sb1,
    const float* __restrict__ sw2, const float* __restrict__ sb2,
    const float* __restrict__ sw3, const float* __restrict__ sb3,
    float* __restrict__ x_cal)
{
    __shared__ float cq[15][256];
    __shared__ float s_w1[48], s_b1[16], s_w2[256], s_b2[16], s_w3[16];
    const int tid = threadIdx.x;
    if (tid < 48) s_w1[tid] = sw1[tid];
    if (tid < 16) { s_b1[tid] = sb1[tid]; s_b2[tid] = sb2[tid]; s_w3[tid] = sw3[tid]; }
    s_w2[tid] = sw2[tid];
#pragma unroll
    for (int k = 0; k < 15; ++k) cq[k][tid] = qs[(k + 1) * 128 * 256 + tid];
    __syncthreads();

    const long b0 = (long)blockIdx.x * 4;
    const int f = tid;
    const float c = center[f];
    const float inv_sc = 1.0f / scale[f];

    float x[4], xr[4];
#pragma unroll
    for (int i = 0; i < 4; ++i) {
        x[i] = x_num[(b0 + i) * F + f];
        xr[i] = (x[i] - c) * inv_sc;
    }

    // coarse: count of subsampled quantiles < x  -> 128-wide window
    int cnt[4] = {0, 0, 0, 0};
#pragma unroll
    for (int k = 0; k < 15; ++k) {
        const float qv = cq[k][f];
#pragma unroll
        for (int i = 0; i < 4; ++i) cnt[i] += (qv < x[i]) ? 1 : 0;
    }
    int lo[4], hi[4];
#pragma unroll
    for (int i = 0; i < 4; ++i) { lo[i] = cnt[i] * 128; hi[i] = lo[i] + 128; }

    // fine: exactly 7 halvings of a 128 window, per-lane contiguous column
    const float* colp = qs_t + (long)f * NQ;
#pragma unroll
    for (int it = 0; it < 7; ++it) {
        int mid[4]; float qv[4];
#pragma unroll
        for (int i = 0; i < 4; ++i) { mid[i] = (lo[i] + hi[i]) >> 1; qv[i] = colp[mid[i]]; }
#pragma unroll
        for (int i = 0; i < 4; ++i) {
            if (qv[i] < x[i]) lo[i] = mid[i] + 1; else hi[i] = mid[i];
        }
    }
    float xq[4];
#pragma unroll
    for (int i = 0; i < 4; ++i)
        xq[i] = fminf((float)lo[i] * (1.0f / (float)(NQ - 1)), 1.0f);

    // stem MLP (4 rows batched; h1 computed on the fly inside the h2 loop)
    float h2[4][16];
#pragma unroll
    for (int j = 0; j < 16; ++j) {
        const float bb = s_b2[j];
#pragma unroll
        for (int i = 0; i < 4; ++i) h2[i][j] = bb;
    }
#pragma unroll 4
    for (int i16 = 0; i16 < 16; ++i16) {
        const float w0 = s_w1[i16], w1v = s_w1[16 + i16], w2v = s_w1[32 + i16];
        const float bb = s_b1[i16];
        float h1v[4];
#pragma unroll
        for (int i = 0; i < 4; ++i)
            h1v[i] = fmaxf(bb + x[i] * w0 + xr[i] * w1v + xq[i] * w2v, 0.0f);
        float wv[16];
        const float4* wr = reinterpret_cast<const float4*>(&s_w2[i16 * 16]);
        *reinterpret_cast<float4*>(&wv[0])  = wr[0];
        *reinterpret_cast<float4*>(&wv[4])  = wr[1];
        *reinterpret_cast<float4*>(&wv[8])  = wr[2];
        *reinterpret_cast<float4*>(&wv[12]) = wr[3];
#pragma unroll
        for (int j = 0; j < 16; ++j) {
#pragma unroll
            for (int i = 0; i < 4; ++i) h2[i][j] += h1v[i] * wv[j];
        }
    }
    float w3v[16];
    {
        const float4* wr = reinterpret_cast<const float4*>(&s_w3[0]);
        *reinterpret_cast<float4*>(&w3v[0])  = wr[0];
        *reinterpret_cast<float4*>(&w3v[4])  = wr[1];
        *reinterpret_cast<float4*>(&w3v[8])  = wr[2];
        *reinterpret_cast<float4*>(&w3v[12]) = wr[3];
    }
    const float b3 = sb3[0];
    float o[4] = {b3, b3, b3, b3};
#pragma unroll
    for (int j = 0; j < 16; ++j) {
#pragma unroll
        for (int i = 0; i < 4; ++i) o[i] += fmaxf(h2[i][j], 0.0f) * w3v[j];
    }
#pragma unroll
    for (int i = 0; i < 4; ++i)
        x_cal[(b0 + i) * F + f] = x[i] + 0.1f * fast_tanh(o[i]);
}

// ---------------------------------------------------------------------------
// k_mfma (unchanged from R4): C = act(A (*mul) @ W + bias), Wt = bf16 W^T
// ---------------------------------------------------------------------------
template <int K, int N, int ACT, int AMODE>
__global__ __launch_bounds__(256) void k_mfma(
    const float* __restrict__ A, const float* __restrict__ mul,
    const short* __restrict__ Wt, const float* __restrict__ bias,
    float* __restrict__ out)
{
    const int tid = threadIdx.x;
    const int wave = tid >> 6;
    const int lane = tid & 63;
    const int sub = lane & 15, quad = lane >> 4;
    const int wm = wave & 1, wn = wave >> 1;
    const long mrow = (long)blockIdx.x * 32 + wm * 16 + sub;
    const int n_base = blockIdx.y * 128 + wn * 64;

    f32x4 acc0 = {0,0,0,0}, acc1 = {0,0,0,0}, acc2 = {0,0,0,0}, acc3 = {0,0,0,0};

#pragma unroll
    for (int k0 = 0; k0 < K; k0 += 32) {
        const float* ap = A + mrow * K + k0 + quad * 8;
        float av[8];
        *reinterpret_cast<float4*>(&av[0]) = *reinterpret_cast<const float4*>(ap);
        *reinterpret_cast<float4*>(&av[4]) = *reinterpret_cast<const float4*>(ap + 4);
        if (AMODE == 1) {
            const float* mp = mul + mrow * K + k0 + quad * 8;
            float mv[8];
            *reinterpret_cast<float4*>(&mv[0]) = *reinterpret_cast<const float4*>(mp);
            *reinterpret_cast<float4*>(&mv[4]) = *reinterpret_cast<const float4*>(mp + 4);
#pragma unroll
            for (int j = 0; j < 8; ++j) av[j] *= mv[j];
        }
        bf16x8 afrag;
#pragma unroll
        for (int j = 0; j < 8; ++j) afrag[j] = f2bf(av[j]);

        const short* bp = Wt + (long)(n_base + sub) * K + k0 + quad * 8;
        const bf16x8 b0 = *reinterpret_cast<const bf16x8*>(bp);
        const bf16x8 b1 = *reinterpret_cast<const bf16x8*>(bp + 16 * K);
        const bf16x8 b2 = *reinterpret_cast<const bf16x8*>(bp + 32 * K);
        const bf16x8 b3 = *reinterpret_cast<const bf16x8*>(bp + 48 * K);
        acc0 = __builtin_amdgcn_mfma_f32_16x16x32_bf16(afrag, b0, acc0, 0, 0, 0);
        acc1 = __builtin_amdgcn_mfma_f32_16x16x32_bf16(afrag, b1, acc1, 0, 0, 0);
        acc2 = __builtin_amdgcn_mfma_f32_16x16x32_bf16(afrag, b2, acc2, 0, 0, 0);
        acc3 = __builtin_amdgcn_mfma_f32_16x16x32_bf16(afrag, b3, acc3, 0, 0, 0);
    }

    const long row_out = (long)blockIdx.x * 32 + wm * 16 + quad * 4;
    const f32x4 accs[4] = {acc0, acc1, acc2, acc3};
#pragma unroll
    for (int t = 0; t < 4; ++t) {
        const int col = n_base + t * 16 + sub;
        const float bb = bias[col];
#pragma unroll
        for (int r = 0; r < 4; ++r) {
            float v = accs[t][r] + bb;
            if (ACT == 0) v = fmaxf(v, 0.0f);
            else          v = 1.0f / (1.0f + __expf(-v));
            out[(row_out + r) * N + col] = v;
        }
    }
}

// ---------------------------------------------------------------------------
// k_topk (unchanged)
// ---------------------------------------------------------------------------
__global__ __launch_bounds__(64) void k_topk(
    const float* __restrict__ g, const float* __restrict__ x_cal,
    const float* __restrict__ tw1, const float* __restrict__ tb1,
    const float* __restrict__ tw2, const float* __restrict__ tb2,
    float* __restrict__ z_top, float* __restrict__ stats)
{
    __shared__ float s_hm[16];
    const int b = blockIdx.x;
    const int lane = threadIdx.x;
    const long base = (long)b * F;

    float gv[4];
#pragma unroll
    for (int i = 0; i < 4; ++i) gv[i] = g[base + lane + 64 * i];

    float s = gv[0] + gv[1] + gv[2] + gv[3];
    float mx = fmaxf(fmaxf(gv[0], gv[1]), fmaxf(gv[2], gv[3]));
    for (int m = 32; m; m >>= 1) {
        s  += __shfl_xor(s, m);
        mx  = fmaxf(mx, __shfl_xor(mx, m));
    }
    const float mean = s * (1.0f / 256.0f);
    float vs = 0.0f;
#pragma unroll
    for (int i = 0; i < 4; ++i) { float d = gv[i] - mean; vs += d * d; }
    for (int m = 32; m; m >>= 1) vs += __shfl_xor(vs, m);
    const float stdv = sqrtf(vs * (1.0f / 256.0f));

    float cur[4]; int curi[4];
#pragma unroll
    for (int i = 0; i < 4; ++i) { cur[i] = gv[i]; curi[i] = lane + 64 * i; }
    float tv[KTOP]; int ti[KTOP]; float vsum = 0.0f;
    for (int r = 0; r < KTOP; ++r) {
        float bv = cur[0]; int bi = curi[0];
#pragma unroll
        for (int i = 1; i < 4; ++i)
            if (cur[i] > bv || (cur[i] == bv && curi[i] < bi)) { bv = cur[i]; bi = curi[i]; }
        for (int m = 32; m; m >>= 1) {
            float ov = __shfl_xor(bv, m);
            int   oi = __shfl_xor(bi, m);
            if (ov > bv || (ov == bv && oi < bi)) { bv = ov; bi = oi; }
        }
        tv[r] = bv; ti[r] = bi; vsum += bv;
#pragma unroll
        for (int i = 0; i < 4; ++i) if (curi[i] == bi) cur[i] = -INFINITY;
    }
    const float denom = 1.0f / (vsum + 1e-6f);

    if (lane < 16) {
        float hm = 0.0f;
        for (int k = 0; k < KTOP; ++k) {
            const float xk = x_cal[base + ti[k]];
            const float xw = xk * (tv[k] * denom);
            hm += fmaxf(xw * tw1[lane] + tb1[lane], 0.0f);
        }
        s_hm[lane] = hm * (1.0f / (float)KTOP);
    }
    __syncthreads();
    if (lane < 16) {
        float z = tb2[lane];
#pragma unroll
        for (int j = 0; j < 16; ++j) z += s_hm[j] * tw2[j * 16 + lane];
        z_top[(long)b * TS + lane] = z;
    }
    if (lane == 0) {
        stats[(long)b * 4 + 0] = mean;
        stats[(long)b * 4 + 1] = mx;
        stats[(long)b * 4 + 2] = stdv;
    }
}

// ---------------------------------------------------------------------------
// k_tail2: fused y_base + safe + spec + conf heads, MFMA-based. 32 rows/block.
// ---------------------------------------------------------------------------
static constexpr int HST = 260;   // s_h fp32 stride (bank-spread)
static constexpr int AST = 312;   // s_a bf16 stride (bank-spread, 16B aligned)

template<int KP>
__device__ __forceinline__ void head_mfma(
    const short* sa, const short* __restrict__ Wt,
    const float* __restrict__ b1v, const float* __restrict__ w2v, int Nreal,
    float (*s_red)[32], int wave, int sub, int quad)
{
    const int mt = wave & 1, nh = wave >> 1;
    f32x4 acc[4];
#pragma unroll
    for (int t = 0; t < 4; ++t) acc[t] = (f32x4){0, 0, 0, 0};
#pragma unroll
    for (int k0 = 0; k0 < KP; k0 += 32) {
        const bf16x8 af = *reinterpret_cast<const bf16x8*>(
            &sa[(mt * 16 + sub) * AST + k0 + quad * 8]);
#pragma unroll
        for (int t = 0; t < 4; ++t) {
            const int col = nh * 64 + t * 16 + sub;
            const bf16x8 bf = *reinterpret_cast<const bf16x8*>(
                &Wt[(long)col * KP + k0 + quad * 8]);
            acc[t] = __builtin_amdgcn_mfma_f32_16x16x32_bf16(af, bf, acc[t], 0, 0, 0);
        }
    }
    float rsum[4] = {0, 0, 0, 0};
#pragma unroll
    for (int t = 0; t < 4; ++t) {
        const int col = nh * 64 + t * 16 + sub;
        const float bb = (col < Nreal) ? b1v[col] : 0.0f;
        const float ww = (col < Nreal) ? w2v[col] : 0.0f;
#pragma unroll
        for (int rr = 0; rr < 4; ++rr)
            rsum[rr] += fmaxf(acc[t][rr] + bb, 0.0f) * ww;
    }
#pragma unroll
    for (int rr = 0; rr < 4; ++rr)
        for (int m = 1; m < 16; m <<= 1) rsum[rr] += __shfl_xor(rsum[rr], m);
    if (sub == 0) {
#pragma unroll
        for (int rr = 0; rr < 4; ++rr)
            s_red[nh][mt * 16 + quad * 4 + rr] = rsum[rr];
    }
}

__global__ __launch_bounds__(256) void k_tail2(
    const float* __restrict__ h_base, const float* __restrict__ z_top,
    const float* __restrict__ gstats,
    const float* __restrict__ base_w, const float* __restrict__ base_b,
    const float* __restrict__ safe_lg, const float* __restrict__ safe_lb,
    const short* __restrict__ sw1t, const float* __restrict__ safe_b1,
    const float* __restrict__ safe_w2, const float* __restrict__ safe_b2,
    const float* __restrict__ spec_lg, const float* __restrict__ spec_lb,
    const short* __restrict__ spw1t, const float* __restrict__ spec_b1,
    const float* __restrict__ spec_w2, const float* __restrict__ spec_b2,
    const float* __restrict__ conf_lg, const float* __restrict__ conf_lb,
    const short* __restrict__ cfw1t, const float* __restrict__ conf_b1,
    const float* __restrict__ conf_w2, const float* __restrict__ conf_b2,
    float* __restrict__ out)
{
    __shared__ float s_h[32 * HST];
    __shared__ short s_a[32 * AST];
    __shared__ float s_z[32 * 16];
    __shared__ float s_g[32 * 4];
    __shared__ float s_sc[32 * 14];
    __shared__ float s_red[2][32];

    const int tid = threadIdx.x;
    const int wave = tid >> 6, lane = tid & 63;
    const int sub = lane & 15, quad = lane >> 4;
    const long row0 = (long)blockIdx.x * 32;

    // S0: stage inputs
    for (int idx = tid; idx < 32 * 64; idx += 256) {
        const int r = idx >> 6, q = idx & 63;
        *reinterpret_cast<float4*>(&s_h[r * HST + q * 4]) =
            *reinterpret_cast<const float4*>(&h_base[(row0 + r) * 256 + q * 4]);
    }
    for (int idx = tid; idx < 512; idx += 256) s_z[idx] = z_top[row0 * 16 + idx];
    if (tid < 128) s_g[tid] = gstats[row0 * 4 + tid];
    __syncthreads();

    // S1: per-row raw moments + y_base  (8 lanes per row)
    {
        const int r = wave * 8 + (lane >> 3), l8 = lane & 7;
        float S = 0.0f, SS = 0.0f, Y = 0.0f, Sz = 0.0f, SSz = 0.0f;
#pragma unroll
        for (int i = 0; i < 32; ++i) {
            const int k = l8 + 8 * i;
            const float v = s_h[r * HST + k];
            S += v; SS += v * v; Y += v * base_w[k];
        }
        {
            const float z0 = s_z[r * 16 + l8], z1 = s_z[r * 16 + l8 + 8];
            Sz = z0 + z1; SSz = z0 * z0 + z1 * z1;
        }
#pragma unroll
        for (int m = 1; m < 8; m <<= 1) {
            S += __shfl_xor(S, m); SS += __shfl_xor(SS, m); Y += __shfl_xor(Y, m);
            Sz += __shfl_xor(Sz, m); SSz += __shfl_xor(SSz, m);
        }
        if (l8 == 0) {
            float* sc = &s_sc[r * 14];
            sc[0] = S; sc[1] = SS; sc[2] = Sz; sc[3] = SSz;
            sc[4] = Y + base_b[0];
            const float mu = S * (1.0f / 256.0f);
            sc[5] = mu;
            sc[6] = rsqrtf(SS * (1.0f / 256.0f) - mu * mu + 1e-5f);
            const float musp = (S + Sz) * (1.0f / (float)SPD);
            sc[7] = musp;
            sc[8] = rsqrtf((SS + SSz) * (1.0f / (float)SPD) - musp * musp + 1e-5f);
        }
    }
    __syncthreads();

    // S2a: safe LN -> bf16 A  (pairs of k, packed b32 writes)
    for (int idx = tid; idx < 32 * 128; idx += 256) {
        const int r = idx >> 7, k = (idx & 127) * 2;
        const float mu = s_sc[r * 14 + 5], rs = s_sc[r * 14 + 6];
        const float v0 = (s_h[r * HST + k] - mu) * rs * safe_lg[k] + safe_lb[k];
        const float v1 = (s_h[r * HST + k + 1] - mu) * rs * safe_lg[k + 1] + safe_lb[k + 1];
        const unsigned pk = (unsigned)(unsigned short)f2bf(v0) |
                            ((unsigned)(unsigned short)f2bf(v1) << 16);
        *reinterpret_cast<unsigned*>(&s_a[r * AST + k]) = pk;
    }
    __syncthreads();

    // S2b: safe MFMA
    head_mfma<256>(s_a, sw1t, safe_b1, safe_w2, 128, s_red, wave, sub, quad);
    __syncthreads();

    // S2c: dsafe  +  S3a: spec LN -> bf16 A
    if (tid < 32) s_sc[tid * 14 + 9] = s_red[0][tid] + s_red[1][tid] + safe_b2[0];
    for (int idx = tid; idx < 32 * 144; idx += 256) {
        const int r = idx / 144, k = (idx - r * 144) * 2;
        const float mu = s_sc[r * 14 + 7], rs = s_sc[r * 14 + 8];
        float v0, v1;
        {
            const int kk = k;
            float raw = (kk < 256) ? s_h[r * HST + kk]
                       : (kk < SPD) ? s_z[r * 16 + kk - 256] : 0.0f;
            v0 = (kk < SPD) ? (raw - mu) * rs * spec_lg[kk] + spec_lb[kk] : 0.0f;
        }
        {
            const int kk = k + 1;
            float raw = (kk < 256) ? s_h[r * HST + kk]
                       : (kk < SPD) ? s_z[r * 16 + kk - 256] : 0.0f;
            v1 = (kk < SPD) ? (raw - mu) * rs * spec_lg[kk] + spec_lb[kk] : 0.0f;
        }
        const unsigned pk = (unsigned)(unsigned short)f2bf(v0) |
                            ((unsigned)(unsigned short)f2bf(v1) << 16);
        *reinterpret_cast<unsigned*>(&s_a[r * AST + k]) = pk;
    }
    __syncthreads();

    // S3b: spec MFMA
    head_mfma<288>(s_a, spw1t, spec_b1, spec_w2, SPH, s_red, wave, sub, quad);
    __syncthreads();

    // S3c: dspec + conf LN stats
    if (tid < 32) {
        float* sc = &s_sc[tid * 14];
        const float dsp = s_red[0][tid] + s_red[1][tid] + spec_b2[0];
        sc[10] = dsp;
        const float yb = sc[4];
        const float gm = s_g[tid * 4 + 0], gx = s_g[tid * 4 + 1], gs = s_g[tid * 4 + 2];
        const float ads = fabsf(sc[9]), adp = fabsf(dsp);
        const float es = yb + gm + gx + gs + ads + adp;
        const float eq = yb * yb + gm * gm + gx * gx + gs * gs + ads * ads + adp * adp;
        const float muc = (sc[0] + sc[2] + es) * (1.0f / (float)CD);
        sc[11] = muc;
        sc[12] = rsqrtf((sc[1] + sc[3] + eq) * (1.0f / (float)CD) - muc * muc + 1e-5f);
    }
    __syncthreads();

    // S4a: conf LN -> bf16 A
    for (int idx = tid; idx < 32 * 144; idx += 256) {
        const int r = idx / 144, k = (idx - r * 144) * 2;
        const float mu = s_sc[r * 14 + 11], rs = s_sc[r * 14 + 12];
        float vv[2];
#pragma unroll
        for (int h = 0; h < 2; ++h) {
            const int kk = k + h;
            float raw;
            if (kk < 256)       raw = s_h[r * HST + kk];
            else if (kk == 256) raw = s_sc[r * 14 + 4];
            else if (kk == 257) raw = s_g[r * 4 + 0];
            else if (kk == 258) raw = s_g[r * 4 + 1];
            else if (kk == 259) raw = s_g[r * 4 + 2];
            else if (kk < 276)  raw = s_z[r * 16 + kk - 260];
            else if (kk == 276) raw = fabsf(s_sc[r * 14 + 9]);
            else if (kk == 277) raw = fabsf(s_sc[r * 14 + 10]);
            else                raw = 0.0f;
            vv[h] = (kk < CD) ? (raw - mu) * rs * conf_lg[kk] + conf_lb[kk] : 0.0f;
        }
        const unsigned pk = (unsigned)(unsigned short)f2bf(vv[0]) |
                            ((unsigned)(unsigned short)f2bf(vv[1]) << 16);
        *reinterpret_cast<unsigned*>(&s_a[r * AST + k]) = pk;
    }
    __syncthreads();

    // S4b: conf MFMA
    head_mfma<288>(s_a, cfw1t, conf_b1, conf_w2, CH, s_red, wave, sub, quad);
    __syncthreads();

    // S4c: gamma + output
    if (tid < 32) {
        const float* sc = &s_sc[tid * 14];
        const float gamma = 1.0f / (1.0f + __expf(-(s_red[0][tid] + s_red[1][tid] + conf_b2[0])));
        out[row0 + tid] = sc[4] + sc[9] + gamma * sc[10];
    }
}

// ---------------------------------------------------------------------------
extern "C" void kernel_launch(void* const* d_in, const int* in_sizes, int n_in,
                              void* d_out, int out_size, void* d_ws, size_t ws_size,
                              hipStream_t stream)
{
    const float* x_num   = (const float*)d_in[0];
    const float* center  = (const float*)d_in[1];
    const float* scale   = (const float*)d_in[2];
    const float* qs      = (const float*)d_in[3];
    const float* stem_w1 = (const float*)d_in[4];
    const float* stem_b1 = (const float*)d_in[5];
    const float* stem_w2 = (const float*)d_in[6];
    const float* stem_b2 = (const float*)d_in[7];
    const float* stem_w3 = (const float*)d_in[8];
    const float* stem_b3 = (const float*)d_in[9];
    const float* gate_w1 = (const float*)d_in[10];
    const float* gate_b1 = (const float*)d_in[11];
    const float* gate_w2 = (const float*)d_in[12];
    const float* gate_b2 = (const float*)d_in[13];
    const float* bb_w    = (const float*)d_in[14];
    const float* bb_b    = (const float*)d_in[15];
    const float* base_w  = (const float*)d_in[16];
    const float* base_b  = (const float*)d_in[17];
    const float* safe_lg = (const float*)d_in[18];
    const float* safe_lb = (const float*)d_in[19];
    const float* safe_w1 = (const float*)d_in[20];
    const float* safe_b1 = (const float*)d_in[21];
    const float* safe_w2 = (const float*)d_in[22];
    const float* safe_b2 = (const float*)d_in[23];
    const float* top_w1  = (const float*)d_in[24];
    const float* top_b1  = (const float*)d_in[25];
    const float* top_w2  = (const float*)d_in[26];
    const float* top_b2  = (const float*)d_in[27];
    const float* spec_lg = (const float*)d_in[28];
    const float* spec_lb = (const float*)d_in[29];
    const float* spec_w1 = (const float*)d_in[30];
    const float* spec_b1 = (const float*)d_in[31];
    const float* spec_w2 = (const float*)d_in[32];
    const float* spec_b2 = (const float*)d_in[33];
    const float* conf_lg = (const float*)d_in[34];
    const float* conf_lb = (const float*)d_in[35];
    const float* conf_w1 = (const float*)d_in[36];
    const float* conf_b1 = (const float*)d_in[37];
    const float* conf_w2 = (const float*)d_in[38];
    const float* conf_b2 = (const float*)d_in[39];

    float* ws    = (float*)d_ws;
    float* x_cal = ws;                         // B*256
    float* g_h   = x_cal + (long)B * 256;      // B*128
    float* g     = g_h   + (long)B * 128;      // B*256
    float* h_b   = g     + (long)B * 256;      // B*256  (qs_t aliases this region pre-backbone)
    float* z_top = h_b   + (long)B * 256;      // B*16
    float* gstat = z_top + (long)B * 16;       // B*4
    short* w1t   = (short*)(gstat + (long)B * 4);  // 128*256
    short* w2t   = w1t   + 128 * 256;              // 256*128
    short* bbt   = w2t   + 256 * 128;              // 256*256
    short* sw1t  = bbt   + 256 * 256;              // 128*256
    short* spw1t = sw1t  + 128 * 256;              // 128*288
    short* cfw1t = spw1t + 128 * 288;              // 128*288
    float* qs_t  = h_b;                            // 256*2048 floats, alias (freed before backbone)
    float* out   = (float*)d_out;

    k_prepall<<<2976, 256, 0, stream>>>(gate_w1, gate_w2, bb_w, safe_w1, spec_w1,
                                        conf_w1, qs,
                                        w1t, w2t, bbt, sw1t, spw1t, cfw1t, qs_t);
    k_calib3<<<B / 4, 256, 0, stream>>>(x_num, center, scale, qs, qs_t,
                                        stem_w1, stem_b1, stem_w2, stem_b2, stem_w3, stem_b3,
                                        x_cal);
    k_mfma<256, 128, 0, 0><<<dim3(B / 32, 1), 256, 0, stream>>>(x_cal, nullptr, w1t, gate_b1, g_h);
    k_mfma<128, 256, 1, 0><<<dim3(B / 32, 2), 256, 0, stream>>>(g_h, nullptr, w2t, gate_b2, g);
    k_topk<<<B, 64, 0, stream>>>(g, x_cal, top_w1, top_b1, top_w2, top_b2, z_top, gstat);
    k_mfma<256, 256, 0, 1><<<dim3(B / 32, 2), 256, 0, stream>>>(x_cal, g, bbt, bb_b, h_b);
    k_tail2<<<B / 32, 256, 0, stream>>>(h_b, z_top, gstat,
                                        base_w, base_b,
                                        safe_lg, safe_lb, sw1t, safe_b1, safe_w2, safe_b2,
                                        spec_lg, spec_lb, spw1t, spec_b1, spec_w2, spec_b2,
                                        conf_lg, conf_lb, cfw1t, conf_b1, conf_w2, conf_b2,
                                        out);
}